// Round 2
// baseline (805.203 us; speedup 1.0000x reference)
//
#include <hip/hip_runtime.h>
#include <hip/hip_bf16.h>

// Problem constants
#define B_    4
#define C_    192
#define C2_   384
#define PIX_  16384      // 128*128
#define NH_   6
#define BG_   1024
#define SCALE_ 0.17677669529663687f   // 32^-0.5
#define NEGM_ (-17.677669529663685f)  // -100 * SCALE_

// ---------------------------------------------------------------------------
// Kernel 0: RoPE cos/sin table: tbl[pos][j] = (cos, sin)(pos * 10^(-j/4)),
// pos in [0,256), j in [0,16). 10000^(-2j/32) == 10^(-j/4).
// ---------------------------------------------------------------------------
__global__ __launch_bounds__(256, 1)
void k_rope_init(float2* __restrict__ tbl) {
    int e = blockIdx.x * 256 + threadIdx.x;    // 4096 entries
    if (e >= 4096) return;
    int pos = e >> 4, j = e & 15;
    float freq = powf(10.0f, -0.25f * (float)j);
    float ang = (float)pos * freq;
    float sn, cs;
    sincosf(ang, &sn, &cs);
    tbl[e] = make_float2(cs, sn);
}

// ---------------------------------------------------------------------------
// Kernel 1: pointwise conv 192->384 (+bias), output bf16.
// Block tile: 64 out-ch x 256 pixels. 256 thr: thread = (og = t>>6, pg = t&63)
// owns 16 oc x 4 px accumulators.
// ---------------------------------------------------------------------------
__global__ __launch_bounds__(256, 4)
void k_conv(const float* __restrict__ x, const float* __restrict__ w,
            const float* __restrict__ bias, __hip_bfloat16* __restrict__ xs)
{
    __shared__ __align__(16) float xt[32][256];
    __shared__ __align__(16) float wt[32][64];
    const int bid = blockIdx.x;
    const int oct = bid % 6;
    const int rest = bid / 6;
    const int b = rest >> 6, pt = rest & 63;
    const int t = threadIdx.x;
    const int pg = t & 63, og = t >> 6;

    float acc[16][4];
#pragma unroll
    for (int i = 0; i < 16; ++i)
#pragma unroll
        for (int r = 0; r < 4; ++r) acc[i][r] = 0.0f;

    for (int c0 = 0; c0 < C_; c0 += 32) {
        __syncthreads();
#pragma unroll
        for (int e0 = 0; e0 < 8; ++e0) {          // x chunk: 32c x 256px
            int e = e0 * 256 + t;
            int cc = e >> 6, f = e & 63;
            *(float4*)&xt[cc][f * 4] =
                *(const float4*)(x + (size_t)(b * C_ + c0 + cc) * PIX_ + pt * 256 + f * 4);
        }
#pragma unroll
        for (int e0 = 0; e0 < 2; ++e0) {          // w chunk transposed: [32c][64oc]
            int e = e0 * 256 + t;
            int o = e >> 3, f = e & 7;
            float4 v = *(const float4*)(w + (size_t)(oct * 64 + o) * C_ + c0 + f * 4);
            wt[f * 4 + 0][o] = v.x; wt[f * 4 + 1][o] = v.y;
            wt[f * 4 + 2][o] = v.z; wt[f * 4 + 3][o] = v.w;
        }
        __syncthreads();
#pragma unroll 4
        for (int c = 0; c < 32; ++c) {
            float4 xv4 = *(const float4*)&xt[c][pg * 4];
            float xv[4] = {xv4.x, xv4.y, xv4.z, xv4.w};
#pragma unroll
            for (int i2 = 0; i2 < 4; ++i2) {
                float4 wv4 = *(const float4*)&wt[c][og * 16 + i2 * 4];
                float wv[4] = {wv4.x, wv4.y, wv4.z, wv4.w};
#pragma unroll
                for (int k = 0; k < 4; ++k)
#pragma unroll
                    for (int r = 0; r < 4; ++r)
                        acc[i2 * 4 + k][r] = fmaf(wv[k], xv[r], acc[i2 * 4 + k][r]);
            }
        }
    }
    const int pxb = pt * 256 + pg * 4;
#pragma unroll
    for (int i = 0; i < 16; ++i) {
        const int oc = oct * 64 + og * 16 + i;
        const float bo = bias[oc];
        union { uint2 u; __hip_bfloat16 hh[4]; } pk;
#pragma unroll
        for (int r = 0; r < 4; ++r) pk.hh[r] = __float2bfloat16(acc[i][r] + bo);
        *(uint2*)(xs + (size_t)(b * C2_ + oc) * PIX_ + pxb) = pk.u;
    }
}

// ---------------------------------------------------------------------------
// Kernel 2: per-window q projection + bias + RoPE + l2norm.
// Block = one window bg, 384 thr: thread = (n = t&63 token, h = t>>6 head),
// computes the head's 32 dims. Wave == head -> LDS w reads are broadcasts.
// qout layout: [bg][h][n][32] f32.
// ---------------------------------------------------------------------------
__global__ __launch_bounds__(384, 3)
void k_qproj(const float* __restrict__ x, const float* __restrict__ wg,
             const float* __restrict__ bgb, const float2* __restrict__ tbl,
             float* __restrict__ qout)
{
    __shared__ __align__(16) float xgT[64][64];   // [c][n]
    __shared__ __align__(16) float wl[C_][64];    // [oc][c]
    const int bg = blockIdx.x;
    const int b = bg >> 8, gh = (bg >> 4) & 15, gw = bg & 15;
    const int t = threadIdx.x;
    const int n = t & 63, h = t >> 6;
    float acc[32];
#pragma unroll
    for (int d = 0; d < 32; ++d) acc[d] = 0.0f;

    for (int c0 = 0; c0 < C_; c0 += 64) {
        __syncthreads();
        for (int e = t; e < 512; e += 384) {      // gather window, transposed
            int c = e >> 3, i = e & 7;
            const float* src = x + (size_t)(b * C_ + c0 + c) * PIX_ + (gh * 8 + i) * 128 + gw * 8;
            *(float4*)&xgT[c][i * 8]     = *(const float4*)src;
            *(float4*)&xgT[c][i * 8 + 4] = *(const float4*)(src + 4);
        }
        for (int e = t; e < 3072; e += 384) {     // w_group chunk [192][64]
            int oc = e >> 4, f = e & 15;
            *(float4*)&wl[oc][f * 4] = *(const float4*)(wg + (size_t)oc * C_ + c0 + f * 4);
        }
        __syncthreads();
#pragma unroll 4
        for (int c = 0; c < 64; c += 4) {
            float xv[4];
#pragma unroll
            for (int j = 0; j < 4; ++j) xv[j] = xgT[c + j][n];
#pragma unroll
            for (int d = 0; d < 32; ++d) {
                float4 wv = *(const float4*)&wl[h * 32 + d][c];
                acc[d] = fmaf(wv.x, xv[0], acc[d]);
                acc[d] = fmaf(wv.y, xv[1], acc[d]);
                acc[d] = fmaf(wv.z, xv[2], acc[d]);
                acc[d] = fmaf(wv.w, xv[3], acc[d]);
            }
        }
    }
#pragma unroll
    for (int d = 0; d < 32; ++d) acc[d] += bgb[h * 32 + d];
    float r[32];
#pragma unroll
    for (int j = 0; j < 16; ++j) {                // interleaved RoPE, pos = n
        float2 cs = tbl[n * 16 + j];
        float a0 = acc[2 * j], a1 = acc[2 * j + 1];
        r[2 * j]     = a0 * cs.x - a1 * cs.y;
        r[2 * j + 1] = a1 * cs.x + a0 * cs.y;
    }
    float n2 = 0.0f;
#pragma unroll
    for (int d = 0; d < 32; ++d) n2 = fmaf(r[d], r[d], n2);
    const float inv = 1.0f / fmaxf(sqrtf(n2), 1e-12f);
    float* dst = qout + ((size_t)(bg * NH_ + h) * 64 + n) * 32;
#pragma unroll
    for (int d4 = 0; d4 < 8; ++d4) {
        float4 v = make_float4(r[d4 * 4] * inv, r[d4 * 4 + 1] * inv,
                               r[d4 * 4 + 2] * inv, r[d4 * 4 + 3] * inv);
        *(float4*)(dst + d4 * 4) = v;
    }
}

// ---------------------------------------------------------------------------
// Kernel 3: attention for one (bg, head). 512 thr = 8 waves; wave w owns
// m in [32w, 32w+32), lane = q-token n. K/V rows in LDS with 16B-chunk XOR
// swizzle (chunk cd stored at cd^(m&7)) -> conflict-free b128 writes,
// broadcast b128 reads. Two-pass softmax with cross-wave LDS reduce.
// graph is int32 (harness promotes jnp bool -> int); each thread compresses
// its 32 mask ints into one 32-bit register bitmask.
// Output written to attn[bg][n][h*32+d] (= d_out, reused as scratch).
// ---------------------------------------------------------------------------
__global__ __launch_bounds__(512, 4)
void k_attn(const __hip_bfloat16* __restrict__ xs, const int* __restrict__ graph,
            const float* __restrict__ q, const float2* __restrict__ tbl,
            float* __restrict__ attn)
{
    __shared__ __align__(16) float sh[16384 + 512];
    float* kl  = sh;            // [256][32] swizzled
    float* fl  = sh + 8192;     // [256][32] swizzled
    float* red = sh + 16384;    // [8][64]

    const int bid = blockIdx.x;
    const int h = bid % NH_;
    const int bg = bid / NH_;
    const int b = bg >> 8, ph = (bg >> 4) & 15, pw = bg & 15;
    const int t = threadIdx.x;
    const int w = t >> 6, lane = t & 63;

    // ---- stage K (rope+norm) and V: thread = (m = t>>1, half = t&1) ----
    {
        const int m = t >> 1, half = t & 1, d0 = half * 16;
        const int k0 = m >> 4, k1 = m & 15;
        const int rr = ph * 8 - 4 + k0, cc2 = pw * 8 - 4 + k1;
        const bool inb = ((unsigned)rr < 128u) && ((unsigned)cc2 < 128u);
        float kv[16], fv[16];
        if (inb) {
            const __hip_bfloat16* pk = xs + (size_t)(b * C2_ + h * 32 + d0) * PIX_ + rr * 128 + cc2;
#pragma unroll
            for (int d = 0; d < 16; ++d) {
                kv[d] = __bfloat162float(pk[(size_t)d * PIX_]);
                fv[d] = __bfloat162float(pk[(size_t)(C_ + d) * PIX_]);
            }
        } else {
#pragma unroll
            for (int d = 0; d < 16; ++d) { kv[d] = 0.0f; fv[d] = 0.0f; }
        }
#pragma unroll
        for (int p = 0; p < 8; ++p) {             // RoPE, pos = m
            float2 cs = tbl[m * 16 + half * 8 + p];
            float a0 = kv[2 * p], a1 = kv[2 * p + 1];
            kv[2 * p]     = a0 * cs.x - a1 * cs.y;
            kv[2 * p + 1] = a1 * cs.x + a0 * cs.y;
        }
        float n2 = 0.0f;
#pragma unroll
        for (int d = 0; d < 16; ++d) n2 = fmaf(kv[d], kv[d], n2);
        n2 += __shfl_xor(n2, 1);                  // combine the two halves
        const float inv = 1.0f / fmaxf(sqrtf(n2), 1e-12f);
#pragma unroll
        for (int q4 = 0; q4 < 4; ++q4) {
            const int cd = half * 4 + q4;
            const int sw = cd ^ (m & 7);
            float4 vk = make_float4(kv[q4 * 4] * inv, kv[q4 * 4 + 1] * inv,
                                    kv[q4 * 4 + 2] * inv, kv[q4 * 4 + 3] * inv);
            float4 vf = make_float4(fv[q4 * 4], fv[q4 * 4 + 1], fv[q4 * 4 + 2], fv[q4 * 4 + 3]);
            *(float4*)&kl[m * 32 + sw * 4] = vk;
            *(float4*)&fl[m * 32 + sw * 4] = vf;
        }
    }

    float qreg[32];
    {
        const float* qp = q + ((size_t)(bg * NH_ + h) * 64 + lane) * 32;
#pragma unroll
        for (int d4 = 0; d4 < 8; ++d4) {
            float4 v = *(const float4*)(qp + d4 * 4);
            qreg[d4 * 4] = v.x; qreg[d4 * 4 + 1] = v.y;
            qreg[d4 * 4 + 2] = v.z; qreg[d4 * 4 + 3] = v.w;
        }
    }
    // graph[bg, 0, n=lane, w*32 .. w*32+32) as int32 -> 32-bit bitmask
    unsigned int mask = 0u;
    {
        const uint4* gp = (const uint4*)(graph + (size_t)bg * 16384 + lane * 256 + w * 32);
#pragma unroll
        for (int g4 = 0; g4 < 8; ++g4) {
            uint4 v = gp[g4];
            mask |= (v.x ? 1u : 0u) << (g4 * 4);
            mask |= (v.y ? 1u : 0u) << (g4 * 4 + 1);
            mask |= (v.z ? 1u : 0u) << (g4 * 4 + 2);
            mask |= (v.w ? 1u : 0u) << (g4 * 4 + 3);
        }
    }
    __syncthreads();

    // ---- sim = q . k ----
    float s[32];
#pragma unroll
    for (int j = 0; j < 32; ++j) {
        const float* row = &kl[(w * 32 + j) * 32];
        float a0 = 0.f, a1 = 0.f, a2 = 0.f, a3 = 0.f;
#pragma unroll
        for (int cd = 0; cd < 8; ++cd) {
            float4 kv4 = *(const float4*)&row[(cd ^ (j & 7)) * 4];
            a0 = fmaf(kv4.x, qreg[cd * 4],     a0);
            a1 = fmaf(kv4.y, qreg[cd * 4 + 1], a1);
            a2 = fmaf(kv4.z, qreg[cd * 4 + 2], a2);
            a3 = fmaf(kv4.w, qreg[cd * 4 + 3], a3);
        }
        s[j] = (a0 + a1) + (a2 + a3);
    }
    // ---- mask + scale + softmax (two-pass, cross-wave via LDS) ----
    float lmax = -3.0e38f;
#pragma unroll
    for (int j = 0; j < 32; ++j) {
        s[j] = s[j] * SCALE_ + (((mask >> j) & 1u) ? 0.0f : NEGM_);
        lmax = fmaxf(lmax, s[j]);
    }
    red[w * 64 + lane] = lmax;
    __syncthreads();
    float M = red[lane];
#pragma unroll
    for (int w2 = 1; w2 < 8; ++w2) M = fmaxf(M, red[w2 * 64 + lane]);
    __syncthreads();
    float lsum = 0.0f;
#pragma unroll
    for (int j = 0; j < 32; ++j) { s[j] = __expf(s[j] - M); lsum += s[j]; }
    red[w * 64 + lane] = lsum;
    __syncthreads();
    float S = 0.0f;
#pragma unroll
    for (int w2 = 0; w2 < 8; ++w2) S += red[w2 * 64 + lane];
    const float invS = 1.0f / S;

    // ---- PV ----
    float o[32];
#pragma unroll
    for (int d = 0; d < 32; ++d) o[d] = 0.0f;
#pragma unroll
    for (int j = 0; j < 32; ++j) {
        const float* row = &fl[(w * 32 + j) * 32];
        const float p = s[j];
#pragma unroll
        for (int cd = 0; cd < 8; ++cd) {
            float4 fv4 = *(const float4*)&row[(cd ^ (j & 7)) * 4];
            o[cd * 4]     = fmaf(p, fv4.x, o[cd * 4]);
            o[cd * 4 + 1] = fmaf(p, fv4.y, o[cd * 4 + 1]);
            o[cd * 4 + 2] = fmaf(p, fv4.z, o[cd * 4 + 2]);
            o[cd * 4 + 3] = fmaf(p, fv4.w, o[cd * 4 + 3]);
        }
    }
    __syncthreads();   // all waves done reading kl/fl -> reuse as partial buf
#pragma unroll
    for (int cd = 0; cd < 8; ++cd) {
        float4 v = make_float4(o[cd * 4] * invS, o[cd * 4 + 1] * invS,
                               o[cd * 4 + 2] * invS, o[cd * 4 + 3] * invS);
        *(float4*)&sh[w * 2048 + lane * 32 + (cd ^ (lane & 7)) * 4] = v;
    }
    __syncthreads();
    {
        const int n2i = t >> 3, cd = t & 7;
        const int sw = (cd ^ (n2i & 7)) * 4;
        float4 a4 = make_float4(0.f, 0.f, 0.f, 0.f);
#pragma unroll
        for (int w2 = 0; w2 < 8; ++w2) {
            float4 v = *(const float4*)&sh[w2 * 2048 + n2i * 32 + sw];
            a4.x += v.x; a4.y += v.y; a4.z += v.z; a4.w += v.w;
        }
        *(float4*)(attn + ((size_t)bg * 64 + n2i) * 192 + h * 32 + cd * 4) = a4;
    }
}

// ---------------------------------------------------------------------------
// Kernel 4: final projection, in-place on d_out. Same structure as k_qproj
// (block = window, thread = (n,h)); each block reads only its own 64 rows
// fully before writing them -> in-place safe.
// ---------------------------------------------------------------------------
__global__ __launch_bounds__(384, 3)
void k_oproj(const float* __restrict__ attn, const float* __restrict__ wp,
             const float* __restrict__ bp, float* __restrict__ out)
{
    __shared__ __align__(16) float aT[64][64];
    __shared__ __align__(16) float wl[C_][64];
    const int bg = blockIdx.x;
    const int t = threadIdx.x;
    const int n = t & 63, h = t >> 6;
    float acc[32];
#pragma unroll
    for (int d = 0; d < 32; ++d) acc[d] = 0.0f;

    for (int c0 = 0; c0 < C_; c0 += 64) {
        __syncthreads();
        for (int e = t; e < 1024; e += 384) {
            int row = e >> 4, f = e & 15;
            float4 v = *(const float4*)(attn + ((size_t)bg * 64 + row) * 192 + c0 + f * 4);
            aT[f * 4 + 0][row] = v.x; aT[f * 4 + 1][row] = v.y;
            aT[f * 4 + 2][row] = v.z; aT[f * 4 + 3][row] = v.w;
        }
        for (int e = t; e < 3072; e += 384) {
            int oc = e >> 4, f = e & 15;
            *(float4*)&wl[oc][f * 4] = *(const float4*)(wp + (size_t)oc * C_ + c0 + f * 4);
        }
        __syncthreads();
#pragma unroll 4
        for (int c = 0; c < 64; c += 4) {
            float xv[4];
#pragma unroll
            for (int j = 0; j < 4; ++j) xv[j] = aT[c + j][n];
#pragma unroll
            for (int d = 0; d < 32; ++d) {
                float4 wv = *(const float4*)&wl[h * 32 + d][c];
                acc[d] = fmaf(wv.x, xv[0], acc[d]);
                acc[d] = fmaf(wv.y, xv[1], acc[d]);
                acc[d] = fmaf(wv.z, xv[2], acc[d]);
                acc[d] = fmaf(wv.w, xv[3], acc[d]);
            }
        }
    }
    float* dst = out + ((size_t)bg * 64 + n) * 192 + h * 32;
#pragma unroll
    for (int d4 = 0; d4 < 8; ++d4) {
        float4 v = make_float4(acc[d4 * 4]     + bp[h * 32 + d4 * 4],
                               acc[d4 * 4 + 1] + bp[h * 32 + d4 * 4 + 1],
                               acc[d4 * 4 + 2] + bp[h * 32 + d4 * 4 + 2],
                               acc[d4 * 4 + 3] + bp[h * 32 + d4 * 4 + 3]);
        *(float4*)(dst + d4 * 4) = v;
    }
}

// ---------------------------------------------------------------------------
extern "C" void kernel_launch(void* const* d_in, const int* in_sizes, int n_in,
                              void* d_out, int out_size, void* d_ws, size_t ws_size,
                              hipStream_t stream)
{
    (void)in_sizes; (void)n_in; (void)out_size; (void)ws_size;
    const float* x   = (const float*)d_in[0];
    const int* grph  = (const int*)d_in[1];     // jnp bool -> int32 per harness
    const float* wg  = (const float*)d_in[2];
    const float* bgb = (const float*)d_in[3];
    const float* wsm = (const float*)d_in[4];
    const float* bsm = (const float*)d_in[5];
    const float* wp  = (const float*)d_in[6];
    const float* bp  = (const float*)d_in[7];
    float* out = (float*)d_out;

    char* wsb = (char*)d_ws;
    __hip_bfloat16* xs = (__hip_bfloat16*)wsb;         // 50,331,648 B (conv out, bf16)
    float* qbuf = (float*)(wsb + 50331648ull);         // 50,331,648 B (roped+normed q)
    float2* tbl = (float2*)(wsb + 100663296ull);       // 32,768 B (rope table)

    hipLaunchKernelGGL(k_rope_init, dim3(16),   dim3(256), 0, stream, tbl);
    hipLaunchKernelGGL(k_conv,      dim3(1536), dim3(256), 0, stream, x, wsm, bsm, xs);
    hipLaunchKernelGGL(k_qproj,     dim3(1024), dim3(384), 0, stream, x, wg, bgb, tbl, qbuf);
    hipLaunchKernelGGL(k_attn,      dim3(6144), dim3(512), 0, stream, xs, grph, qbuf, tbl, out);
    hipLaunchKernelGGL(k_oproj,     dim3(1024), dim3(384), 0, stream, out, wp, bp, out);
}

// Round 3
// 617.118 us; speedup vs baseline: 1.3048x; 1.3048x over previous
//
#include <hip/hip_runtime.h>
#include <hip/hip_bf16.h>

// Problem constants
#define B_    4
#define C_    192
#define C2_   384
#define PIX_  16384      // 128*128
#define NH_   6
#define BG_   1024
#define SCALE_ 0.17677669529663687f   // 32^-0.5
#define NEGM_ (-17.677669529663685f)  // -100 * SCALE_

typedef __attribute__((ext_vector_type(8))) short short8v;   // 8 bf16 = 4 VGPR
typedef __attribute__((ext_vector_type(4))) float f32x4;

// ---------------------------------------------------------------------------
// Kernel 0: RoPE cos/sin table
// ---------------------------------------------------------------------------
__global__ __launch_bounds__(256, 1)
void k_rope_init(float2* __restrict__ tbl) {
    int e = blockIdx.x * 256 + threadIdx.x;    // 4096 entries
    if (e >= 4096) return;
    int pos = e >> 4, j = e & 15;
    float freq = powf(10.0f, -0.25f * (float)j);
    float ang = (float)pos * freq;
    float sn, cs;
    sincosf(ang, &sn, &cs);
    tbl[e] = make_float2(cs, sn);
}

// ---------------------------------------------------------------------------
// Kernel 0b: compress graph int32 -> bitmask. gbits[bg*512 + q*8 + wd] bit i
// = graph[bg][q][wd*32+i] != 0.
// ---------------------------------------------------------------------------
__global__ __launch_bounds__(256, 4)
void k_gmask(const int* __restrict__ g, unsigned int* __restrict__ gbits) {
    int e = blockIdx.x * 256 + threadIdx.x;            // 524288 dwords
    const uint4* p = (const uint4*)(g + (size_t)e * 32);
    unsigned int m = 0u;
#pragma unroll
    for (int i = 0; i < 8; ++i) {
        uint4 v = p[i];
        m |= (v.x ? 1u : 0u) << (i * 4);
        m |= (v.y ? 1u : 0u) << (i * 4 + 1);
        m |= (v.z ? 1u : 0u) << (i * 4 + 2);
        m |= (v.w ? 1u : 0u) << (i * 4 + 3);
    }
    gbits[e] = m;
}

// ---------------------------------------------------------------------------
// Kernel 1: pointwise conv 192->384 (+bias), output bf16.  (unchanged)
// ---------------------------------------------------------------------------
__global__ __launch_bounds__(256, 4)
void k_conv(const float* __restrict__ x, const float* __restrict__ w,
            const float* __restrict__ bias, __hip_bfloat16* __restrict__ xs)
{
    __shared__ __align__(16) float xt[32][256];
    __shared__ __align__(16) float wt[32][64];
    const int bid = blockIdx.x;
    const int oct = bid % 6;
    const int rest = bid / 6;
    const int b = rest >> 6, pt = rest & 63;
    const int t = threadIdx.x;
    const int pg = t & 63, og = t >> 6;

    float acc[16][4];
#pragma unroll
    for (int i = 0; i < 16; ++i)
#pragma unroll
        for (int r = 0; r < 4; ++r) acc[i][r] = 0.0f;

    for (int c0 = 0; c0 < C_; c0 += 32) {
        __syncthreads();
#pragma unroll
        for (int e0 = 0; e0 < 8; ++e0) {
            int e = e0 * 256 + t;
            int cc = e >> 6, f = e & 63;
            *(float4*)&xt[cc][f * 4] =
                *(const float4*)(x + (size_t)(b * C_ + c0 + cc) * PIX_ + pt * 256 + f * 4);
        }
#pragma unroll
        for (int e0 = 0; e0 < 2; ++e0) {
            int e = e0 * 256 + t;
            int o = e >> 3, f = e & 7;
            float4 v = *(const float4*)(w + (size_t)(oct * 64 + o) * C_ + c0 + f * 4);
            wt[f * 4 + 0][o] = v.x; wt[f * 4 + 1][o] = v.y;
            wt[f * 4 + 2][o] = v.z; wt[f * 4 + 3][o] = v.w;
        }
        __syncthreads();
#pragma unroll 4
        for (int c = 0; c < 32; ++c) {
            float4 xv4 = *(const float4*)&xt[c][pg * 4];
            float xv[4] = {xv4.x, xv4.y, xv4.z, xv4.w};
#pragma unroll
            for (int i2 = 0; i2 < 4; ++i2) {
                float4 wv4 = *(const float4*)&wt[c][og * 16 + i2 * 4];
                float wv[4] = {wv4.x, wv4.y, wv4.z, wv4.w};
#pragma unroll
                for (int k = 0; k < 4; ++k)
#pragma unroll
                    for (int r = 0; r < 4; ++r)
                        acc[i2 * 4 + k][r] = fmaf(wv[k], xv[r], acc[i2 * 4 + k][r]);
            }
        }
    }
    const int pxb = pt * 256 + pg * 4;
#pragma unroll
    for (int i = 0; i < 16; ++i) {
        const int oc = oct * 64 + og * 16 + i;
        const float bo = bias[oc];
        union { uint2 u; __hip_bfloat16 hh[4]; } pk;
#pragma unroll
        for (int r = 0; r < 4; ++r) pk.hh[r] = __float2bfloat16(acc[i][r] + bo);
        *(uint2*)(xs + (size_t)(b * C2_ + oc) * PIX_ + pxb) = pk.u;
    }
}

// ---------------------------------------------------------------------------
// Kernel 2: per-window q projection + bias + RoPE + l2norm -> bf16.
// qout layout: [bg][h][n][32] bf16 (MFMA A-frag ready).
// ---------------------------------------------------------------------------
__global__ __launch_bounds__(384, 3)
void k_qproj(const float* __restrict__ x, const float* __restrict__ wg,
             const float* __restrict__ bgb, const float2* __restrict__ tbl,
             __hip_bfloat16* __restrict__ qout)
{
    __shared__ __align__(16) float xgT[64][64];
    __shared__ __align__(16) float wl[C_][64];
    const int bg = blockIdx.x;
    const int b = bg >> 8, gh = (bg >> 4) & 15, gw = bg & 15;
    const int t = threadIdx.x;
    const int n = t & 63, h = t >> 6;
    float acc[32];
#pragma unroll
    for (int d = 0; d < 32; ++d) acc[d] = 0.0f;

    for (int c0 = 0; c0 < C_; c0 += 64) {
        __syncthreads();
        for (int e = t; e < 512; e += 384) {
            int c = e >> 3, i = e & 7;
            const float* src = x + (size_t)(b * C_ + c0 + c) * PIX_ + (gh * 8 + i) * 128 + gw * 8;
            *(float4*)&xgT[c][i * 8]     = *(const float4*)src;
            *(float4*)&xgT[c][i * 8 + 4] = *(const float4*)(src + 4);
        }
        for (int e = t; e < 3072; e += 384) {
            int oc = e >> 4, f = e & 15;
            *(float4*)&wl[oc][f * 4] = *(const float4*)(wg + (size_t)oc * C_ + c0 + f * 4);
        }
        __syncthreads();
#pragma unroll 4
        for (int c = 0; c < 64; c += 4) {
            float xv[4];
#pragma unroll
            for (int j = 0; j < 4; ++j) xv[j] = xgT[c + j][n];
#pragma unroll
            for (int d = 0; d < 32; ++d) {
                float4 wv = *(const float4*)&wl[h * 32 + d][c];
                acc[d] = fmaf(wv.x, xv[0], acc[d]);
                acc[d] = fmaf(wv.y, xv[1], acc[d]);
                acc[d] = fmaf(wv.z, xv[2], acc[d]);
                acc[d] = fmaf(wv.w, xv[3], acc[d]);
            }
        }
    }
#pragma unroll
    for (int d = 0; d < 32; ++d) acc[d] += bgb[h * 32 + d];
    float r[32];
#pragma unroll
    for (int j = 0; j < 16; ++j) {
        float2 cs = tbl[n * 16 + j];
        float a0 = acc[2 * j], a1 = acc[2 * j + 1];
        r[2 * j]     = a0 * cs.x - a1 * cs.y;
        r[2 * j + 1] = a1 * cs.x + a0 * cs.y;
    }
    float n2 = 0.0f;
#pragma unroll
    for (int d = 0; d < 32; ++d) n2 = fmaf(r[d], r[d], n2);
    const float inv = 1.0f / fmaxf(sqrtf(n2), 1e-12f);
    __hip_bfloat16* dst = qout + ((size_t)(bg * NH_ + h) * 64 + n) * 32;
#pragma unroll
    for (int c8 = 0; c8 < 4; ++c8) {
        union { uint4 u; __hip_bfloat16 hh[8]; } pk;
#pragma unroll
        for (int i = 0; i < 8; ++i) pk.hh[i] = __float2bfloat16(r[c8 * 8 + i] * inv);
        *(uint4*)(dst + c8 * 8) = pk.u;
    }
}

// ---------------------------------------------------------------------------
// Kernel 3 (MFMA): attention for one (bg, head). 512 thr = 8 waves.
// Wave w: q-rows rbase=(w&3)*16, kv-half cb=(w>>2)*128.
// sim: mfma_16x16x32_bf16, A = Q frags (global), B = K rows (LDS, 80B pad).
// softmax: per-lane over 8 tiles + shfl_xor(1,2,4,8) + LDS cross-half.
// PV: A = P (per-wave LDS transpose, 272B rows), B = V^T (LDS, 528B pad).
// LDS map (bytes):
//   [0,20480)  kl bf16 [256 tok][40]  -- overlaid later by pl/obuf
//   [20480,22784) gb uint [64][9]     -- overlaid later by pl
//   [0,34816)  pl per-wave 4352B = 16 rows x 272B   (after softmax)
//   [0,8448)   obuf f32 [64][33]                    (after PV)
//   [34816,51712) vl bf16 [32 d][264] (528B rows)
//   [51712,52736) redmax f32[128], redsum f32[128]
// ---------------------------------------------------------------------------
__global__ __launch_bounds__(512, 2)
void k_attn(const __hip_bfloat16* __restrict__ xs, const unsigned int* __restrict__ gbits,
            const __hip_bfloat16* __restrict__ qb, const float2* __restrict__ tbl,
            float* __restrict__ attn)
{
    __shared__ __align__(16) char smem[52736];
    const int bid = blockIdx.x;
    const int h = bid % NH_;
    const int bg = bid / NH_;
    const int b = bg >> 8, ph = (bg >> 4) & 15, pw = bg & 15;
    const int t = threadIdx.x;
    const int w = t >> 6, lane = t & 63;
    const int g = lane >> 4, l15 = lane & 15;
    const int rbase = (w & 3) * 16;        // q rows
    const int wcol  = w >> 2;              // kv half
    const int cb    = wcol * 128;
    const int cb32  = wcol * 4;

    // ---- A-frag: Q direct from global (issue early) ----
    const short8v qa = *(const short8v*)(qb +
        ((size_t)(bg * NH_ + h) * 64 + rbase + l15) * 32 + g * 8);

    // ---- stage K (rope+norm, bf16) into kl: thread=(m=t>>1, half=t&1) ----
    {
        const int m = t >> 1, half = t & 1;
        const int k0 = m >> 4, k1 = m & 15;
        const int rr = ph * 8 - 4 + k0, cc = pw * 8 - 4 + k1;
        const bool inb = ((unsigned)rr < 128u) && ((unsigned)cc < 128u);
        float kv[16];
        const __hip_bfloat16* pk = xs + (size_t)(b * C2_ + h * 32 + half * 16) * PIX_ + rr * 128 + cc;
        if (inb) {
#pragma unroll
            for (int d = 0; d < 16; ++d) kv[d] = __bfloat162float(pk[(size_t)d * PIX_]);
        } else {
#pragma unroll
            for (int d = 0; d < 16; ++d) kv[d] = 0.0f;
        }
#pragma unroll
        for (int p = 0; p < 8; ++p) {
            float2 cs = tbl[m * 16 + half * 8 + p];
            float a0 = kv[2 * p], a1 = kv[2 * p + 1];
            kv[2 * p]     = a0 * cs.x - a1 * cs.y;
            kv[2 * p + 1] = a1 * cs.x + a0 * cs.y;
        }
        float n2 = 0.0f;
#pragma unroll
        for (int d = 0; d < 16; ++d) n2 = fmaf(kv[d], kv[d], n2);
        n2 += __shfl_xor(n2, 1);
        const float inv = 1.0f / fmaxf(sqrtf(n2), 1e-12f);
        union { uint4 u; __hip_bfloat16 hh[8]; } p0, p1;
#pragma unroll
        for (int i = 0; i < 8; ++i) {
            p0.hh[i] = __float2bfloat16(kv[i] * inv);
            p1.hh[i] = __float2bfloat16(kv[8 + i] * inv);
        }
        *(uint4*)(smem + m * 80 + half * 32)      = p0.u;
        *(uint4*)(smem + m * 80 + half * 32 + 16) = p1.u;
    }

    // ---- stage V transposed into vl[d][kv] (528B rows): thread=(d=t&31,k0=t>>5) ----
    {
        const int d = t & 31, k0 = t >> 5;
        const int rr = ph * 8 - 4 + k0;
        const int c0 = pw * 8 - 4;
        char* dst = smem + 34816 + d * 528 + k0 * 32;
        const __hip_bfloat16* src = xs + (size_t)(b * C2_ + C_ + h * 32 + d) * PIX_ + rr * 128 + c0;
        const bool rok = (unsigned)rr < 128u;
        if (rok && pw >= 1 && pw <= 14) {
            const uint2* s2 = (const uint2*)src;   // 8B aligned
            uint2 a0 = s2[0], a1 = s2[1], a2 = s2[2], a3 = s2[3];
            ((uint4*)dst)[0] = make_uint4(a0.x, a0.y, a1.x, a1.y);
            ((uint4*)dst)[1] = make_uint4(a2.x, a2.y, a3.x, a3.y);
        } else {
            __hip_bfloat16* dh = (__hip_bfloat16*)dst;
            __hip_bfloat16 z = __float2bfloat16(0.0f);
#pragma unroll
            for (int i = 0; i < 16; ++i) {
                bool ok = rok && ((unsigned)(c0 + i) < 128u);
                dh[i] = ok ? src[i] : z;
            }
        }
    }

    // ---- stage graph bits: gb[q][9] uints ----
    {
        unsigned int* gbl = (unsigned int*)(smem + 20480);
        const int q = t >> 3, wd = t & 7;
        gbl[q * 9 + wd] = gbits[(size_t)bg * 512 + t];
    }
    __syncthreads();   // sync1

    // ---- sim = Q K^T : 8 tiles of 16x16, K=32 in one MFMA each ----
    f32x4 acc[8];
    const f32x4 zz = {0.0f, 0.0f, 0.0f, 0.0f};
#pragma unroll
    for (int tile = 0; tile < 8; ++tile) {
        const short8v kb = *(const short8v*)(smem + (cb + tile * 16 + l15) * 80 + g * 16);
        acc[tile] = __builtin_amdgcn_mfma_f32_16x16x32_bf16(qa, kb, zz, 0, 0, 0);
    }

    // ---- mask + scale + row max ----
    const unsigned int* gbl = (const unsigned int*)(smem + 20480);
    float* redm = (float*)(smem + 51712);
    float* reds = (float*)(smem + 51712 + 512);
    float mx4[4], Mt[4], sm4[4], inv4[4];
#pragma unroll
    for (int j = 0; j < 4; ++j) {
        const int q = rbase + g * 4 + j;
        const unsigned int wv[4] = { gbl[q * 9 + cb32], gbl[q * 9 + cb32 + 1],
                                     gbl[q * 9 + cb32 + 2], gbl[q * 9 + cb32 + 3] };
        float mx = -3.0e38f;
#pragma unroll
        for (int tile = 0; tile < 8; ++tile) {
            unsigned int bit = (wv[tile >> 1] >> ((tile & 1) * 16 + l15)) & 1u;
            float s = acc[tile][j] * SCALE_ + (bit ? 0.0f : NEGM_);
            acc[tile][j] = s;
            mx = fmaxf(mx, s);
        }
        mx = fmaxf(mx, __shfl_xor(mx, 1));
        mx = fmaxf(mx, __shfl_xor(mx, 2));
        mx = fmaxf(mx, __shfl_xor(mx, 4));
        mx = fmaxf(mx, __shfl_xor(mx, 8));
        mx4[j] = mx;
        if (l15 == 0) redm[wcol * 64 + q] = mx;
    }
    __syncthreads();   // sync2
#pragma unroll
    for (int j = 0; j < 4; ++j) {
        const int q = rbase + g * 4 + j;
        Mt[j] = fmaxf(mx4[j], redm[(wcol ^ 1) * 64 + q]);
        float sm = 0.0f;
#pragma unroll
        for (int tile = 0; tile < 8; ++tile) {
            float e = __expf(acc[tile][j] - Mt[j]);
            acc[tile][j] = e;
            sm += e;
        }
        sm += __shfl_xor(sm, 1);
        sm += __shfl_xor(sm, 2);
        sm += __shfl_xor(sm, 4);
        sm += __shfl_xor(sm, 8);
        sm4[j] = sm;
        if (l15 == 0) reds[wcol * 64 + q] = sm;
    }
    __syncthreads();   // sync3
#pragma unroll
    for (int j = 0; j < 4; ++j) {
        const int q = rbase + g * 4 + j;
        inv4[j] = 1.0f / (sm4[j] + reds[(wcol ^ 1) * 64 + q]);
    }

    // ---- write P (bf16) to per-wave pl region (overlays kl/gb; safe: 2 syncs ago) ----
    char* plw = smem + w * 4352;
#pragma unroll
    for (int tile = 0; tile < 8; ++tile)
#pragma unroll
        for (int j = 0; j < 4; ++j) {
            *(__hip_bfloat16*)(plw + (g * 4 + j) * 272 + (tile * 16 + l15) * 2) =
                __float2bfloat16(acc[tile][j] * inv4[j]);
        }

    // ---- PV: out[16 q][32 d] partial over this wave's kv half ----
    f32x4 o0 = zz, o1 = zz;
#pragma unroll
    for (int ks = 0; ks < 4; ++ks) {
        const short8v pa  = *(const short8v*)(plw + l15 * 272 + (ks * 32 + g * 8) * 2);
        const short8v vb0 = *(const short8v*)(smem + 34816 + l15 * 528        + (cb + ks * 32 + g * 8) * 2);
        const short8v vb1 = *(const short8v*)(smem + 34816 + (16 + l15) * 528 + (cb + ks * 32 + g * 8) * 2);
        o0 = __builtin_amdgcn_mfma_f32_16x16x32_bf16(pa, vb0, o0, 0, 0, 0);
        o1 = __builtin_amdgcn_mfma_f32_16x16x32_bf16(pa, vb1, o1, 0, 0, 0);
    }
    __syncthreads();   // sync4: all PV reads of pl/vl done

    // ---- cross-half reduce + store ----
    float* ob = (float*)smem;   // [64][33] f32
    if (wcol == 1) {
#pragma unroll
        for (int j = 0; j < 4; ++j) {
            const int q = rbase + g * 4 + j;
            ob[q * 33 + l15]      = o0[j];
            ob[q * 33 + 16 + l15] = o1[j];
        }
    }
    __syncthreads();   // sync5
    if (wcol == 0) {
#pragma unroll
        for (int j = 0; j < 4; ++j) {
            const int q = rbase + g * 4 + j;
            float v0 = o0[j] + ob[q * 33 + l15];
            float v1 = o1[j] + ob[q * 33 + 16 + l15];
            attn[((size_t)bg * 64 + q) * 192 + h * 32 + l15]      = v0;
            attn[((size_t)bg * 64 + q) * 192 + h * 32 + 16 + l15] = v1;
        }
    }
}

// ---------------------------------------------------------------------------
// Kernel 4: final projection, in-place on d_out.  (unchanged)
// ---------------------------------------------------------------------------
__global__ __launch_bounds__(384, 3)
void k_oproj(const float* __restrict__ attn, const float* __restrict__ wp,
             const float* __restrict__ bp, float* __restrict__ out)
{
    __shared__ __align__(16) float aT[64][64];
    __shared__ __align__(16) float wl[C_][64];
    const int bg = blockIdx.x;
    const int t = threadIdx.x;
    const int n = t & 63, h = t >> 6;
    float acc[32];
#pragma unroll
    for (int d = 0; d < 32; ++d) acc[d] = 0.0f;

    for (int c0 = 0; c0 < C_; c0 += 64) {
        __syncthreads();
        for (int e = t; e < 1024; e += 384) {
            int row = e >> 4, f = e & 15;
            float4 v = *(const float4*)(attn + ((size_t)bg * 64 + row) * 192 + c0 + f * 4);
            aT[f * 4 + 0][row] = v.x; aT[f * 4 + 1][row] = v.y;
            aT[f * 4 + 2][row] = v.z; aT[f * 4 + 3][row] = v.w;
        }
        for (int e = t; e < 3072; e += 384) {
            int oc = e >> 4, f = e & 15;
            *(float4*)&wl[oc][f * 4] = *(const float4*)(wp + (size_t)oc * C_ + c0 + f * 4);
        }
        __syncthreads();
#pragma unroll 4
        for (int c = 0; c < 64; c += 4) {
            float xv[4];
#pragma unroll
            for (int j = 0; j < 4; ++j) xv[j] = aT[c + j][n];
#pragma unroll
            for (int d = 0; d < 32; ++d) {
                float4 wv = *(const float4*)&wl[h * 32 + d][c];
                acc[d] = fmaf(wv.x, xv[0], acc[d]);
                acc[d] = fmaf(wv.y, xv[1], acc[d]);
                acc[d] = fmaf(wv.z, xv[2], acc[d]);
                acc[d] = fmaf(wv.w, xv[3], acc[d]);
            }
        }
    }
    float* dst = out + ((size_t)bg * 64 + n) * 192 + h * 32;
#pragma unroll
    for (int d4 = 0; d4 < 8; ++d4) {
        float4 v = make_float4(acc[d4 * 4]     + bp[h * 32 + d4 * 4],
                               acc[d4 * 4 + 1] + bp[h * 32 + d4 * 4 + 1],
                               acc[d4 * 4 + 2] + bp[h * 32 + d4 * 4 + 2],
                               acc[d4 * 4 + 3] + bp[h * 32 + d4 * 4 + 3]);
        *(float4*)(dst + d4 * 4) = v;
    }
}

// ---------------------------------------------------------------------------
extern "C" void kernel_launch(void* const* d_in, const int* in_sizes, int n_in,
                              void* d_out, int out_size, void* d_ws, size_t ws_size,
                              hipStream_t stream)
{
    (void)in_sizes; (void)n_in; (void)out_size; (void)ws_size;
    const float* x   = (const float*)d_in[0];
    const int* grph  = (const int*)d_in[1];     // jnp bool -> int32 per harness
    const float* wg  = (const float*)d_in[2];
    const float* bgb = (const float*)d_in[3];
    const float* wsm = (const float*)d_in[4];
    const float* bsm = (const float*)d_in[5];
    const float* wp  = (const float*)d_in[6];
    const float* bp  = (const float*)d_in[7];
    float* out = (float*)d_out;

    char* wsb = (char*)d_ws;
    __hip_bfloat16* xs = (__hip_bfloat16*)wsb;               // 50,331,648 B (conv out, bf16)
    __hip_bfloat16* qbf = (__hip_bfloat16*)(wsb + 50331648ull); // 25,165,824 B (q bf16)
    float2* tbl = (float2*)(wsb + 75497472ull);              // 32,768 B (rope table)
    unsigned int* gbits = (unsigned int*)(wsb + 75530240ull);// 2,097,152 B (graph bitmask)

    hipLaunchKernelGGL(k_rope_init, dim3(16),   dim3(256), 0, stream, tbl);
    hipLaunchKernelGGL(k_gmask,     dim3(2048), dim3(256), 0, stream, grph, gbits);
    hipLaunchKernelGGL(k_conv,      dim3(1536), dim3(256), 0, stream, x, wsm, bsm, xs);
    hipLaunchKernelGGL(k_qproj,     dim3(1024), dim3(384), 0, stream, x, wg, bgb, tbl, qbf);
    hipLaunchKernelGGL(k_attn,      dim3(6144), dim3(512), 0, stream, xs, gbits, qbf, tbl, out);
    hipLaunchKernelGGL(k_oproj,     dim3(1024), dim3(384), 0, stream, out, wp, bp, out);
}

// Round 4
// 386.699 us; speedup vs baseline: 2.0822x; 1.5959x over previous
//
#include <hip/hip_runtime.h>
#include <hip/hip_bf16.h>

// Problem constants
#define B_    4
#define C_    192
#define C2_   384
#define PIX_  16384      // 128*128
#define NH_   6
#define BG_   1024
#define SCALE_ 0.17677669529663687f   // 32^-0.5
#define NEGM_ (-17.677669529663685f)  // -100 * SCALE_

typedef __attribute__((ext_vector_type(8))) short short8v;   // 8 bf16 = 4 VGPR
typedef __attribute__((ext_vector_type(4))) float f32x4;

// ---------------------------------------------------------------------------
// Kernel 0: RoPE cos/sin table
// ---------------------------------------------------------------------------
__global__ __launch_bounds__(256, 1)
void k_rope_init(float2* __restrict__ tbl) {
    int e = blockIdx.x * 256 + threadIdx.x;    // 4096 entries
    if (e >= 4096) return;
    int pos = e >> 4, j = e & 15;
    float freq = powf(10.0f, -0.25f * (float)j);
    float ang = (float)pos * freq;
    float sn, cs;
    sincosf(ang, &sn, &cs);
    tbl[e] = make_float2(cs, sn);
}

// ---------------------------------------------------------------------------
// Kernel 0b: graph int32 -> bitmask
// ---------------------------------------------------------------------------
__global__ __launch_bounds__(256, 4)
void k_gmask(const int* __restrict__ g, unsigned int* __restrict__ gbits) {
    int e = blockIdx.x * 256 + threadIdx.x;            // 524288 dwords
    const uint4* p = (const uint4*)(g + (size_t)e * 32);
    unsigned int m = 0u;
#pragma unroll
    for (int i = 0; i < 8; ++i) {
        uint4 v = p[i];
        m |= (v.x ? 1u : 0u) << (i * 4);
        m |= (v.y ? 1u : 0u) << (i * 4 + 1);
        m |= (v.z ? 1u : 0u) << (i * 4 + 2);
        m |= (v.w ? 1u : 0u) << (i * 4 + 3);
    }
    gbits[e] = m;
}

// ---------------------------------------------------------------------------
// Kernel 0c: cast w_sample [384x192] ++ w_group [192x192] -> wb bf16 [576][192]
// ---------------------------------------------------------------------------
__global__ __launch_bounds__(256, 4)
void k_wcast(const float* __restrict__ wsm, const float* __restrict__ wgb,
             __hip_bfloat16* __restrict__ wb)
{
    int e = (blockIdx.x * 256 + threadIdx.x) * 4;      // 110592 elems
    float4 v = (e < 73728) ? *(const float4*)(wsm + e)
                           : *(const float4*)(wgb + (e - 73728));
    union { uint2 u; __hip_bfloat16 h[4]; } pk;
    pk.h[0] = __float2bfloat16(v.x); pk.h[1] = __float2bfloat16(v.y);
    pk.h[2] = __float2bfloat16(v.z); pk.h[3] = __float2bfloat16(v.w);
    *(uint2*)(wb + e) = pk.u;
}

// ---------------------------------------------------------------------------
// Kernel 1 (MFMA): fused 1x1 conv 192 -> 576 (w_sample 384 + w_group 192).
// Block: 64 px x 64 oc, K=192 fully staged in LDS (400B-padded bf16 rows).
// 4 waves, wave = 32px x 32oc quadrant, 24 mfma_16x16x32_bf16 each.
// oct<6 -> xs bf16 [b][384][pix]; oct>=6 -> q path: epilogue applies bias +
// RoPE(n) + l2norm per (pixel, head) and writes qbf [bg][h][n][32] bf16.
// XCD-chunk swizzle: 9 oc-tiles of one px-tile land on one XCD (L2 reuse).
// ---------------------------------------------------------------------------
__global__ __launch_bounds__(256, 4)
void k_convm(const float* __restrict__ x, const __hip_bfloat16* __restrict__ wb,
             const float* __restrict__ bsm, const float* __restrict__ bgb,
             const float2* __restrict__ tbl,
             __hip_bfloat16* __restrict__ xs, __hip_bfloat16* __restrict__ qbf)
{
    __shared__ __align__(16) char smem[25600];   // xt [64px][400B] / ot [64oc][272B]
    const int bid0 = blockIdx.x;
    const int bid = (bid0 & 7) * 1152 + (bid0 >> 3);   // 9216 = 8 x 1152, bijective
    const int oct = bid % 9;
    const int pb  = bid / 9;
    const int b = pb >> 8, pt = pb & 255;
    const int px0 = pt * 64;
    const int t = threadIdx.x;

    // ---- stage x tile [64 px][192 c] -> bf16 LDS, transposed ----
    {
        const int px = t & 63, cq = t >> 6;
        const float* src = x + ((size_t)b * C_ + cq * 48) * PIX_ + px0 + px;
        char* row = smem + px * 400 + cq * 96;
#pragma unroll
        for (int i = 0; i < 6; ++i) {
            union { uint4 u; __hip_bfloat16 h[8]; } pk;
#pragma unroll
            for (int j = 0; j < 8; ++j)
                pk.h[j] = __float2bfloat16(src[(size_t)(i * 8 + j) * PIX_]);
            *(uint4*)(row + i * 16) = pk.u;
        }
    }
    __syncthreads();

    const int w = t >> 6, lane = t & 63;
    const int l15 = lane & 15, g = lane >> 4;
    const int mb = (w & 1) * 32;     // px quadrant
    const int nb = (w >> 1) * 32;    // oc quadrant

    const f32x4 zz = {0.0f, 0.0f, 0.0f, 0.0f};
    f32x4 acc00 = zz, acc01 = zz, acc10 = zz, acc11 = zz;
    const __hip_bfloat16* w0 = wb + (size_t)(oct * 64 + nb + l15) * C_;
    const __hip_bfloat16* w1 = w0 + 16 * C_;
#pragma unroll
    for (int ks = 0; ks < 6; ++ks) {
        const short8v a0 = *(const short8v*)(smem + (mb + l15) * 400      + ks * 64 + g * 16);
        const short8v a1 = *(const short8v*)(smem + (mb + 16 + l15) * 400 + ks * 64 + g * 16);
        const short8v b0 = *(const short8v*)(w0 + ks * 32 + g * 8);
        const short8v b1 = *(const short8v*)(w1 + ks * 32 + g * 8);
        acc00 = __builtin_amdgcn_mfma_f32_16x16x32_bf16(a0, b0, acc00, 0, 0, 0);
        acc01 = __builtin_amdgcn_mfma_f32_16x16x32_bf16(a0, b1, acc01, 0, 0, 0);
        acc10 = __builtin_amdgcn_mfma_f32_16x16x32_bf16(a1, b0, acc10, 0, 0, 0);
        acc11 = __builtin_amdgcn_mfma_f32_16x16x32_bf16(a1, b1, acc11, 0, 0, 0);
    }
    __syncthreads();   // A-frag reads done -> overlay ot

    // ---- write f32 tile ot[oc][px] (68-float rows) ----
    float* ot = (float*)smem;
    *(f32x4*)&ot[(nb + l15) * 68      + mb + g * 4]      = acc00;
    *(f32x4*)&ot[(nb + l15) * 68      + mb + 16 + g * 4] = acc10;
    *(f32x4*)&ot[(nb + 16 + l15) * 68 + mb + g * 4]      = acc01;
    *(f32x4*)&ot[(nb + 16 + l15) * 68 + mb + 16 + g * 4] = acc11;
    __syncthreads();

    if (oct < 6) {
        const float* bias = bsm + oct * 64;
#pragma unroll
        for (int e0 = 0; e0 < 2; ++e0) {
            const int e = e0 * 256 + t;
            const int oc = e >> 3, seg = e & 7;
            const float bo = bias[oc];
            float4 v0 = *(const float4*)&ot[oc * 68 + seg * 8];
            float4 v1 = *(const float4*)&ot[oc * 68 + seg * 8 + 4];
            union { uint4 u; __hip_bfloat16 h[8]; } pk;
            pk.h[0] = __float2bfloat16(v0.x + bo); pk.h[1] = __float2bfloat16(v0.y + bo);
            pk.h[2] = __float2bfloat16(v0.z + bo); pk.h[3] = __float2bfloat16(v0.w + bo);
            pk.h[4] = __float2bfloat16(v1.x + bo); pk.h[5] = __float2bfloat16(v1.y + bo);
            pk.h[6] = __float2bfloat16(v1.z + bo); pk.h[7] = __float2bfloat16(v1.w + bo);
            *(uint4*)(xs + (size_t)(b * C2_ + oct * 64 + oc) * PIX_ + px0 + seg * 8) = pk.u;
        }
    } else {
        // q path: bias + RoPE + l2norm per (pixel, head); 2 heads in this tile
        const int px = t & 63, hh = t >> 6;
        if (hh < 2) {
            const int p = px0 + px;
            const int r = p >> 7, c = p & 127;
            const int n = (r & 7) * 8 + (c & 7);
            const int bg = (b << 8) + ((r >> 3) << 4) + (c >> 3);
            const int hglob = (oct - 6) * 2 + hh;
            float v[32];
#pragma unroll
            for (int d = 0; d < 32; ++d)
                v[d] = ot[(hh * 32 + d) * 68 + px] + bgb[hglob * 32 + d];
            float rr[32];
#pragma unroll
            for (int j = 0; j < 16; ++j) {
                float2 cs = tbl[n * 16 + j];
                float a0 = v[2 * j], a1 = v[2 * j + 1];
                rr[2 * j]     = a0 * cs.x - a1 * cs.y;
                rr[2 * j + 1] = a1 * cs.x + a0 * cs.y;
            }
            float n2 = 0.0f;
#pragma unroll
            for (int d = 0; d < 32; ++d) n2 = fmaf(rr[d], rr[d], n2);
            const float inv = 1.0f / fmaxf(sqrtf(n2), 1e-12f);
            __hip_bfloat16* dst = qbf + ((size_t)(bg * NH_ + hglob) * 64 + n) * 32;
#pragma unroll
            for (int c8 = 0; c8 < 4; ++c8) {
                union { uint4 u; __hip_bfloat16 h[8]; } pk;
#pragma unroll
                for (int i = 0; i < 8; ++i) pk.h[i] = __float2bfloat16(rr[c8 * 8 + i] * inv);
                *(uint4*)(dst + c8 * 8) = pk.u;
            }
        }
    }
}

// ---------------------------------------------------------------------------
// Kernel 3 (MFMA): attention for one (bg, head).  (unchanged from round 3)
// ---------------------------------------------------------------------------
__global__ __launch_bounds__(512, 2)
void k_attn(const __hip_bfloat16* __restrict__ xs, const unsigned int* __restrict__ gbits,
            const __hip_bfloat16* __restrict__ qb, const float2* __restrict__ tbl,
            float* __restrict__ attn)
{
    __shared__ __align__(16) char smem[52736];
    const int bid = blockIdx.x;
    const int h = bid % NH_;
    const int bg = bid / NH_;
    const int b = bg >> 8, ph = (bg >> 4) & 15, pw = bg & 15;
    const int t = threadIdx.x;
    const int w = t >> 6, lane = t & 63;
    const int g = lane >> 4, l15 = lane & 15;
    const int rbase = (w & 3) * 16;        // q rows
    const int wcol  = w >> 2;              // kv half
    const int cb    = wcol * 128;
    const int cb32  = wcol * 4;

    // ---- A-frag: Q direct from global (issue early) ----
    const short8v qa = *(const short8v*)(qb +
        ((size_t)(bg * NH_ + h) * 64 + rbase + l15) * 32 + g * 8);

    // ---- stage K (rope+norm, bf16) into kl: thread=(m=t>>1, half=t&1) ----
    {
        const int m = t >> 1, half = t & 1;
        const int k0 = m >> 4, k1 = m & 15;
        const int rr = ph * 8 - 4 + k0, cc = pw * 8 - 4 + k1;
        const bool inb = ((unsigned)rr < 128u) && ((unsigned)cc < 128u);
        float kv[16];
        const __hip_bfloat16* pk = xs + (size_t)(b * C2_ + h * 32 + half * 16) * PIX_ + rr * 128 + cc;
        if (inb) {
#pragma unroll
            for (int d = 0; d < 16; ++d) kv[d] = __bfloat162float(pk[(size_t)d * PIX_]);
        } else {
#pragma unroll
            for (int d = 0; d < 16; ++d) kv[d] = 0.0f;
        }
#pragma unroll
        for (int p = 0; p < 8; ++p) {
            float2 cs = tbl[m * 16 + half * 8 + p];
            float a0 = kv[2 * p], a1 = kv[2 * p + 1];
            kv[2 * p]     = a0 * cs.x - a1 * cs.y;
            kv[2 * p + 1] = a1 * cs.x + a0 * cs.y;
        }
        float n2 = 0.0f;
#pragma unroll
        for (int d = 0; d < 16; ++d) n2 = fmaf(kv[d], kv[d], n2);
        n2 += __shfl_xor(n2, 1);
        const float inv = 1.0f / fmaxf(sqrtf(n2), 1e-12f);
        union { uint4 u; __hip_bfloat16 hh[8]; } p0, p1;
#pragma unroll
        for (int i = 0; i < 8; ++i) {
            p0.hh[i] = __float2bfloat16(kv[i] * inv);
            p1.hh[i] = __float2bfloat16(kv[8 + i] * inv);
        }
        *(uint4*)(smem + m * 80 + half * 32)      = p0.u;
        *(uint4*)(smem + m * 80 + half * 32 + 16) = p1.u;
    }

    // ---- stage V transposed into vl[d][kv] (528B rows): thread=(d=t&31,k0=t>>5) ----
    {
        const int d = t & 31, k0 = t >> 5;
        const int rr = ph * 8 - 4 + k0;
        const int c0 = pw * 8 - 4;
        char* dst = smem + 34816 + d * 528 + k0 * 32;
        const __hip_bfloat16* src = xs + (size_t)(b * C2_ + C_ + h * 32 + d) * PIX_ + rr * 128 + c0;
        const bool rok = (unsigned)rr < 128u;
        if (rok && pw >= 1 && pw <= 14) {
            const uint2* s2 = (const uint2*)src;   // 8B aligned
            uint2 a0 = s2[0], a1 = s2[1], a2 = s2[2], a3 = s2[3];
            ((uint4*)dst)[0] = make_uint4(a0.x, a0.y, a1.x, a1.y);
            ((uint4*)dst)[1] = make_uint4(a2.x, a2.y, a3.x, a3.y);
        } else {
            __hip_bfloat16* dh = (__hip_bfloat16*)dst;
            __hip_bfloat16 z = __float2bfloat16(0.0f);
#pragma unroll
            for (int i = 0; i < 16; ++i) {
                bool ok = rok && ((unsigned)(c0 + i) < 128u);
                dh[i] = ok ? src[i] : z;
            }
        }
    }

    // ---- stage graph bits: gb[q][9] uints ----
    {
        unsigned int* gbl = (unsigned int*)(smem + 20480);
        const int q = t >> 3, wd = t & 7;
        gbl[q * 9 + wd] = gbits[(size_t)bg * 512 + t];
    }
    __syncthreads();   // sync1

    // ---- sim = Q K^T : 8 tiles of 16x16, K=32 in one MFMA each ----
    f32x4 acc[8];
    const f32x4 zz = {0.0f, 0.0f, 0.0f, 0.0f};
#pragma unroll
    for (int tile = 0; tile < 8; ++tile) {
        const short8v kb = *(const short8v*)(smem + (cb + tile * 16 + l15) * 80 + g * 16);
        acc[tile] = __builtin_amdgcn_mfma_f32_16x16x32_bf16(qa, kb, zz, 0, 0, 0);
    }

    // ---- mask + scale + row max ----
    const unsigned int* gbl = (const unsigned int*)(smem + 20480);
    float* redm = (float*)(smem + 51712);
    float* reds = (float*)(smem + 51712 + 512);
    float mx4[4], Mt[4], sm4[4], inv4[4];
#pragma unroll
    for (int j = 0; j < 4; ++j) {
        const int q = rbase + g * 4 + j;
        const unsigned int wv[4] = { gbl[q * 9 + cb32], gbl[q * 9 + cb32 + 1],
                                     gbl[q * 9 + cb32 + 2], gbl[q * 9 + cb32 + 3] };
        float mx = -3.0e38f;
#pragma unroll
        for (int tile = 0; tile < 8; ++tile) {
            unsigned int bit = (wv[tile >> 1] >> ((tile & 1) * 16 + l15)) & 1u;
            float s = acc[tile][j] * SCALE_ + (bit ? 0.0f : NEGM_);
            acc[tile][j] = s;
            mx = fmaxf(mx, s);
        }
        mx = fmaxf(mx, __shfl_xor(mx, 1));
        mx = fmaxf(mx, __shfl_xor(mx, 2));
        mx = fmaxf(mx, __shfl_xor(mx, 4));
        mx = fmaxf(mx, __shfl_xor(mx, 8));
        mx4[j] = mx;
        if (l15 == 0) redm[wcol * 64 + q] = mx;
    }
    __syncthreads();   // sync2
#pragma unroll
    for (int j = 0; j < 4; ++j) {
        const int q = rbase + g * 4 + j;
        Mt[j] = fmaxf(mx4[j], redm[(wcol ^ 1) * 64 + q]);
        float sm = 0.0f;
#pragma unroll
        for (int tile = 0; tile < 8; ++tile) {
            float e = __expf(acc[tile][j] - Mt[j]);
            acc[tile][j] = e;
            sm += e;
        }
        sm += __shfl_xor(sm, 1);
        sm += __shfl_xor(sm, 2);
        sm += __shfl_xor(sm, 4);
        sm += __shfl_xor(sm, 8);
        sm4[j] = sm;
        if (l15 == 0) reds[wcol * 64 + q] = sm;
    }
    __syncthreads();   // sync3
#pragma unroll
    for (int j = 0; j < 4; ++j) {
        const int q = rbase + g * 4 + j;
        inv4[j] = 1.0f / (sm4[j] + reds[(wcol ^ 1) * 64 + q]);
    }

    // ---- write P (bf16) to per-wave pl region ----
    char* plw = smem + w * 4352;
#pragma unroll
    for (int tile = 0; tile < 8; ++tile)
#pragma unroll
        for (int j = 0; j < 4; ++j) {
            *(__hip_bfloat16*)(plw + (g * 4 + j) * 272 + (tile * 16 + l15) * 2) =
                __float2bfloat16(acc[tile][j] * inv4[j]);
        }

    // ---- PV ----
    f32x4 o0 = zz, o1 = zz;
#pragma unroll
    for (int ks = 0; ks < 4; ++ks) {
        const short8v pa  = *(const short8v*)(plw + l15 * 272 + (ks * 32 + g * 8) * 2);
        const short8v vb0 = *(const short8v*)(smem + 34816 + l15 * 528        + (cb + ks * 32 + g * 8) * 2);
        const short8v vb1 = *(const short8v*)(smem + 34816 + (16 + l15) * 528 + (cb + ks * 32 + g * 8) * 2);
        o0 = __builtin_amdgcn_mfma_f32_16x16x32_bf16(pa, vb0, o0, 0, 0, 0);
        o1 = __builtin_amdgcn_mfma_f32_16x16x32_bf16(pa, vb1, o1, 0, 0, 0);
    }
    __syncthreads();   // sync4

    // ---- cross-half reduce + store ----
    float* ob = (float*)smem;   // [64][33] f32
    if (wcol == 1) {
#pragma unroll
        for (int j = 0; j < 4; ++j) {
            const int q = rbase + g * 4 + j;
            ob[q * 33 + l15]      = o0[j];
            ob[q * 33 + 16 + l15] = o1[j];
        }
    }
    __syncthreads();   // sync5
    if (wcol == 0) {
#pragma unroll
        for (int j = 0; j < 4; ++j) {
            const int q = rbase + g * 4 + j;
            float v0 = o0[j] + ob[q * 33 + l15];
            float v1 = o1[j] + ob[q * 33 + 16 + l15];
            attn[((size_t)bg * 64 + q) * 192 + h * 32 + l15]      = v0;
            attn[((size_t)bg * 64 + q) * 192 + h * 32 + 16 + l15] = v1;
        }
    }
}

// ---------------------------------------------------------------------------
// Kernel 4: final projection, in-place on d_out.  (unchanged)
// ---------------------------------------------------------------------------
__global__ __launch_bounds__(384, 3)
void k_oproj(const float* __restrict__ attn, const float* __restrict__ wp,
             const float* __restrict__ bp, float* __restrict__ out)
{
    __shared__ __align__(16) float aT[64][64];
    __shared__ __align__(16) float wl[C_][64];
    const int bg = blockIdx.x;
    const int t = threadIdx.x;
    const int n = t & 63, h = t >> 6;
    float acc[32];
#pragma unroll
    for (int d = 0; d < 32; ++d) acc[d] = 0.0f;

    for (int c0 = 0; c0 < C_; c0 += 64) {
        __syncthreads();
        for (int e = t; e < 1024; e += 384) {
            int row = e >> 4, f = e & 15;
            float4 v = *(const float4*)(attn + ((size_t)bg * 64 + row) * 192 + c0 + f * 4);
            aT[f * 4 + 0][row] = v.x; aT[f * 4 + 1][row] = v.y;
            aT[f * 4 + 2][row] = v.z; aT[f * 4 + 3][row] = v.w;
        }
        for (int e = t; e < 3072; e += 384) {
            int oc = e >> 4, f = e & 15;
            *(float4*)&wl[oc][f * 4] = *(const float4*)(wp + (size_t)oc * C_ + c0 + f * 4);
        }
        __syncthreads();
#pragma unroll 4
        for (int c = 0; c < 64; c += 4) {
            float xv[4];
#pragma unroll
            for (int j = 0; j < 4; ++j) xv[j] = aT[c + j][n];
#pragma unroll
            for (int d = 0; d < 32; ++d) {
                float4 wv = *(const float4*)&wl[h * 32 + d][c];
                acc[d] = fmaf(wv.x, xv[0], acc[d]);
                acc[d] = fmaf(wv.y, xv[1], acc[d]);
                acc[d] = fmaf(wv.z, xv[2], acc[d]);
                acc[d] = fmaf(wv.w, xv[3], acc[d]);
            }
        }
    }
    float* dst = out + ((size_t)bg * 64 + n) * 192 + h * 32;
#pragma unroll
    for (int d4 = 0; d4 < 8; ++d4) {
        float4 v = make_float4(acc[d4 * 4]     + bp[h * 32 + d4 * 4],
                               acc[d4 * 4 + 1] + bp[h * 32 + d4 * 4 + 1],
                               acc[d4 * 4 + 2] + bp[h * 32 + d4 * 4 + 2],
                               acc[d4 * 4 + 3] + bp[h * 32 + d4 * 4 + 3]);
        *(float4*)(dst + d4 * 4) = v;
    }
}

// ---------------------------------------------------------------------------
extern "C" void kernel_launch(void* const* d_in, const int* in_sizes, int n_in,
                              void* d_out, int out_size, void* d_ws, size_t ws_size,
                              hipStream_t stream)
{
    (void)in_sizes; (void)n_in; (void)out_size; (void)ws_size;
    const float* x   = (const float*)d_in[0];
    const int* grph  = (const int*)d_in[1];     // jnp bool -> int32 per harness
    const float* wg  = (const float*)d_in[2];
    const float* bgb = (const float*)d_in[3];
    const float* wsm = (const float*)d_in[4];
    const float* bsm = (const float*)d_in[5];
    const float* wp  = (const float*)d_in[6];
    const float* bp  = (const float*)d_in[7];
    float* out = (float*)d_out;

    char* wsb = (char*)d_ws;
    __hip_bfloat16* xs  = (__hip_bfloat16*)wsb;                  // 50,331,648 B (conv out, bf16)
    __hip_bfloat16* qbf = (__hip_bfloat16*)(wsb + 50331648ull);  // 25,165,824 B (q bf16)
    float2* tbl = (float2*)(wsb + 75497472ull);                  // 32,768 B (rope table)
    unsigned int* gbits = (unsigned int*)(wsb + 75530240ull);    // 2,097,152 B (graph bits)
    __hip_bfloat16* wb  = (__hip_bfloat16*)(wsb + 77627392ull);  // 221,184 B (weights bf16)

    hipLaunchKernelGGL(k_rope_init, dim3(16),   dim3(256), 0, stream, tbl);
    hipLaunchKernelGGL(k_wcast,     dim3(108),  dim3(256), 0, stream, wsm, wg, wb);
    hipLaunchKernelGGL(k_gmask,     dim3(2048), dim3(256), 0, stream, grph, gbits);
    hipLaunchKernelGGL(k_convm,     dim3(9216), dim3(256), 0, stream, x, wb, bsm, bgb, tbl, xs, qbf);
    hipLaunchKernelGGL(k_attn,      dim3(6144), dim3(512), 0, stream, xs, gbits, qbf, tbl, out);
    hipLaunchKernelGGL(k_oproj,     dim3(1024), dim3(384), 0, stream, out, wp, bp, out);
}

// Round 5
// 230.654 us; speedup vs baseline: 3.4910x; 1.6765x over previous
//
#include <hip/hip_runtime.h>
#include <hip/hip_bf16.h>

// Problem constants
#define B_    4
#define C_    192
#define C2_   384
#define PIX_  16384      // 128*128
#define NH_   6
#define BG_   1024
#define SCALE_ 0.17677669529663687f   // 32^-0.5
#define NEGM_ (-17.677669529663685f)  // -100 * SCALE_

typedef __attribute__((ext_vector_type(8))) short short8v;   // 8 bf16 = 4 VGPR
typedef __attribute__((ext_vector_type(4))) float f32x4;

// ---------------------------------------------------------------------------
// Kernel 0: RoPE cos/sin table
// ---------------------------------------------------------------------------
__global__ __launch_bounds__(256, 1)
void k_rope_init(float2* __restrict__ tbl) {
    int e = blockIdx.x * 256 + threadIdx.x;    // 4096 entries
    if (e >= 4096) return;
    int pos = e >> 4, j = e & 15;
    float freq = powf(10.0f, -0.25f * (float)j);
    float ang = (float)pos * freq;
    float sn, cs;
    sincosf(ang, &sn, &cs);
    tbl[e] = make_float2(cs, sn);
}

// ---------------------------------------------------------------------------
// Kernel 0b: graph int32 -> bitmask
// ---------------------------------------------------------------------------
__global__ __launch_bounds__(256, 4)
void k_gmask(const int* __restrict__ g, unsigned int* __restrict__ gbits) {
    int e = blockIdx.x * 256 + threadIdx.x;            // 524288 dwords
    const uint4* p = (const uint4*)(g + (size_t)e * 32);
    unsigned int m = 0u;
#pragma unroll
    for (int i = 0; i < 8; ++i) {
        uint4 v = p[i];
        m |= (v.x ? 1u : 0u) << (i * 4);
        m |= (v.y ? 1u : 0u) << (i * 4 + 1);
        m |= (v.z ? 1u : 0u) << (i * 4 + 2);
        m |= (v.w ? 1u : 0u) << (i * 4 + 3);
    }
    gbits[e] = m;
}

// ---------------------------------------------------------------------------
// Kernel 0c: cast w_sample [384x192] ++ w_group [192x192] ++ w_proj [192x192]
// -> wb bf16 [576][192] ++ wpb bf16 [192][192]
// ---------------------------------------------------------------------------
__global__ __launch_bounds__(256, 4)
void k_wcast(const float* __restrict__ wsm, const float* __restrict__ wgb,
             const float* __restrict__ wpj, __hip_bfloat16* __restrict__ wb)
{
    int e = (blockIdx.x * 256 + threadIdx.x) * 4;      // 147456 elems
    float4 v = (e < 73728) ? *(const float4*)(wsm + e)
             : (e < 110592) ? *(const float4*)(wgb + (e - 73728))
                            : *(const float4*)(wpj + (e - 110592));
    union { uint2 u; __hip_bfloat16 h[4]; } pk;
    pk.h[0] = __float2bfloat16(v.x); pk.h[1] = __float2bfloat16(v.y);
    pk.h[2] = __float2bfloat16(v.z); pk.h[3] = __float2bfloat16(v.w);
    *(uint2*)(wb + e) = pk.u;
}

// ---------------------------------------------------------------------------
// Kernel 1 (MFMA): fused 1x1 conv 192 -> 576 (w_sample 384 + w_group 192).
// Block: 64 px x 64 oc, K=192 fully staged in LDS (400B-padded bf16 rows).
// 4 waves, wave = 32px x 32oc quadrant, 24 mfma_16x16x32_bf16 each.
// oct<6 -> xs bf16 [b][384][pix]; oct>=6 -> q path: epilogue applies bias +
// RoPE(n) + l2norm per (pixel, head) and writes qbf [bg][h][n][32] bf16.
// ---------------------------------------------------------------------------
__global__ __launch_bounds__(256, 4)
void k_convm(const float* __restrict__ x, const __hip_bfloat16* __restrict__ wb,
             const float* __restrict__ bsm, const float* __restrict__ bgb,
             const float2* __restrict__ tbl,
             __hip_bfloat16* __restrict__ xs, __hip_bfloat16* __restrict__ qbf)
{
    __shared__ __align__(16) char smem[25600];   // xt [64px][400B] / ot [64oc][272B]
    const int bid0 = blockIdx.x;
    const int bid = (bid0 & 7) * 1152 + (bid0 >> 3);   // 9216 = 8 x 1152, bijective
    const int oct = bid % 9;
    const int pb  = bid / 9;
    const int b = pb >> 8, pt = pb & 255;
    const int px0 = pt * 64;
    const int t = threadIdx.x;

    // ---- stage x tile [64 px][192 c] -> bf16 LDS, transposed ----
    {
        const int px = t & 63, cq = t >> 6;
        const float* src = x + ((size_t)b * C_ + cq * 48) * PIX_ + px0 + px;
        char* row = smem + px * 400 + cq * 96;
#pragma unroll
        for (int i = 0; i < 6; ++i) {
            union { uint4 u; __hip_bfloat16 h[8]; } pk;
#pragma unroll
            for (int j = 0; j < 8; ++j)
                pk.h[j] = __float2bfloat16(src[(size_t)(i * 8 + j) * PIX_]);
            *(uint4*)(row + i * 16) = pk.u;
        }
    }
    __syncthreads();

    const int w = t >> 6, lane = t & 63;
    const int l15 = lane & 15, g = lane >> 4;
    const int mb = (w & 1) * 32;     // px quadrant
    const int nb = (w >> 1) * 32;    // oc quadrant

    const f32x4 zz = {0.0f, 0.0f, 0.0f, 0.0f};
    f32x4 acc00 = zz, acc01 = zz, acc10 = zz, acc11 = zz;
    const __hip_bfloat16* w0 = wb + (size_t)(oct * 64 + nb + l15) * C_;
    const __hip_bfloat16* w1 = w0 + 16 * C_;
#pragma unroll
    for (int ks = 0; ks < 6; ++ks) {
        const short8v a0 = *(const short8v*)(smem + (mb + l15) * 400      + ks * 64 + g * 16);
        const short8v a1 = *(const short8v*)(smem + (mb + 16 + l15) * 400 + ks * 64 + g * 16);
        const short8v b0 = *(const short8v*)(w0 + ks * 32 + g * 8);
        const short8v b1 = *(const short8v*)(w1 + ks * 32 + g * 8);
        acc00 = __builtin_amdgcn_mfma_f32_16x16x32_bf16(a0, b0, acc00, 0, 0, 0);
        acc01 = __builtin_amdgcn_mfma_f32_16x16x32_bf16(a0, b1, acc01, 0, 0, 0);
        acc10 = __builtin_amdgcn_mfma_f32_16x16x32_bf16(a1, b0, acc10, 0, 0, 0);
        acc11 = __builtin_amdgcn_mfma_f32_16x16x32_bf16(a1, b1, acc11, 0, 0, 0);
    }
    __syncthreads();   // A-frag reads done -> overlay ot

    // ---- write f32 tile ot[oc][px] (68-float rows) ----
    float* ot = (float*)smem;
    *(f32x4*)&ot[(nb + l15) * 68      + mb + g * 4]      = acc00;
    *(f32x4*)&ot[(nb + l15) * 68      + mb + 16 + g * 4] = acc10;
    *(f32x4*)&ot[(nb + 16 + l15) * 68 + mb + g * 4]      = acc01;
    *(f32x4*)&ot[(nb + 16 + l15) * 68 + mb + 16 + g * 4] = acc11;
    __syncthreads();

    if (oct < 6) {
        const float* bias = bsm + oct * 64;
#pragma unroll
        for (int e0 = 0; e0 < 2; ++e0) {
            const int e = e0 * 256 + t;
            const int oc = e >> 3, seg = e & 7;
            const float bo = bias[oc];
            float4 v0 = *(const float4*)&ot[oc * 68 + seg * 8];
            float4 v1 = *(const float4*)&ot[oc * 68 + seg * 8 + 4];
            union { uint4 u; __hip_bfloat16 h[8]; } pk;
            pk.h[0] = __float2bfloat16(v0.x + bo); pk.h[1] = __float2bfloat16(v0.y + bo);
            pk.h[2] = __float2bfloat16(v0.z + bo); pk.h[3] = __float2bfloat16(v0.w + bo);
            pk.h[4] = __float2bfloat16(v1.x + bo); pk.h[5] = __float2bfloat16(v1.y + bo);
            pk.h[6] = __float2bfloat16(v1.z + bo); pk.h[7] = __float2bfloat16(v1.w + bo);
            *(uint4*)(xs + (size_t)(b * C2_ + oct * 64 + oc) * PIX_ + px0 + seg * 8) = pk.u;
        }
    } else {
        // q path: bias + RoPE + l2norm per (pixel, head); 2 heads in this tile
        const int px = t & 63, hh = t >> 6;
        if (hh < 2) {
            const int p = px0 + px;
            const int r = p >> 7, c = p & 127;
            const int n = (r & 7) * 8 + (c & 7);
            const int bg = (b << 8) + ((r >> 3) << 4) + (c >> 3);
            const int hglob = (oct - 6) * 2 + hh;
            float v[32];
#pragma unroll
            for (int d = 0; d < 32; ++d)
                v[d] = ot[(hh * 32 + d) * 68 + px] + bgb[hglob * 32 + d];
            float rr[32];
#pragma unroll
            for (int j = 0; j < 16; ++j) {
                float2 cs = tbl[n * 16 + j];
                float a0 = v[2 * j], a1 = v[2 * j + 1];
                rr[2 * j]     = a0 * cs.x - a1 * cs.y;
                rr[2 * j + 1] = a1 * cs.x + a0 * cs.y;
            }
            float n2 = 0.0f;
#pragma unroll
            for (int d = 0; d < 32; ++d) n2 = fmaf(rr[d], rr[d], n2);
            const float inv = 1.0f / fmaxf(sqrtf(n2), 1e-12f);
            __hip_bfloat16* dst = qbf + ((size_t)(bg * NH_ + hglob) * 64 + n) * 32;
#pragma unroll
            for (int c8 = 0; c8 < 4; ++c8) {
                union { uint4 u; __hip_bfloat16 h[8]; } pk;
#pragma unroll
                for (int i = 0; i < 8; ++i) pk.h[i] = __float2bfloat16(rr[c8 * 8 + i] * inv);
                *(uint4*)(dst + c8 * 8) = pk.u;
            }
        }
    }
}

// ---------------------------------------------------------------------------
// Kernel 3 (MFMA): attention for one (bg, head).  (unchanged from round 3)
// ---------------------------------------------------------------------------
__global__ __launch_bounds__(512, 2)
void k_attn(const __hip_bfloat16* __restrict__ xs, const unsigned int* __restrict__ gbits,
            const __hip_bfloat16* __restrict__ qb, const float2* __restrict__ tbl,
            float* __restrict__ attn)
{
    __shared__ __align__(16) char smem[52736];
    const int bid = blockIdx.x;
    const int h = bid % NH_;
    const int bg = bid / NH_;
    const int b = bg >> 8, ph = (bg >> 4) & 15, pw = bg & 15;
    const int t = threadIdx.x;
    const int w = t >> 6, lane = t & 63;
    const int g = lane >> 4, l15 = lane & 15;
    const int rbase = (w & 3) * 16;        // q rows
    const int wcol  = w >> 2;              // kv half
    const int cb    = wcol * 128;
    const int cb32  = wcol * 4;

    // ---- A-frag: Q direct from global (issue early) ----
    const short8v qa = *(const short8v*)(qb +
        ((size_t)(bg * NH_ + h) * 64 + rbase + l15) * 32 + g * 8);

    // ---- stage K (rope+norm, bf16) into kl: thread=(m=t>>1, half=t&1) ----
    {
        const int m = t >> 1, half = t & 1;
        const int k0 = m >> 4, k1 = m & 15;
        const int rr = ph * 8 - 4 + k0, cc = pw * 8 - 4 + k1;
        const bool inb = ((unsigned)rr < 128u) && ((unsigned)cc < 128u);
        float kv[16];
        const __hip_bfloat16* pk = xs + (size_t)(b * C2_ + h * 32 + half * 16) * PIX_ + rr * 128 + cc;
        if (inb) {
#pragma unroll
            for (int d = 0; d < 16; ++d) kv[d] = __bfloat162float(pk[(size_t)d * PIX_]);
        } else {
#pragma unroll
            for (int d = 0; d < 16; ++d) kv[d] = 0.0f;
        }
#pragma unroll
        for (int p = 0; p < 8; ++p) {
            float2 cs = tbl[m * 16 + half * 8 + p];
            float a0 = kv[2 * p], a1 = kv[2 * p + 1];
            kv[2 * p]     = a0 * cs.x - a1 * cs.y;
            kv[2 * p + 1] = a1 * cs.x + a0 * cs.y;
        }
        float n2 = 0.0f;
#pragma unroll
        for (int d = 0; d < 16; ++d) n2 = fmaf(kv[d], kv[d], n2);
        n2 += __shfl_xor(n2, 1);
        const float inv = 1.0f / fmaxf(sqrtf(n2), 1e-12f);
        union { uint4 u; __hip_bfloat16 hh[8]; } p0, p1;
#pragma unroll
        for (int i = 0; i < 8; ++i) {
            p0.hh[i] = __float2bfloat16(kv[i] * inv);
            p1.hh[i] = __float2bfloat16(kv[8 + i] * inv);
        }
        *(uint4*)(smem + m * 80 + half * 32)      = p0.u;
        *(uint4*)(smem + m * 80 + half * 32 + 16) = p1.u;
    }

    // ---- stage V transposed into vl[d][kv] (528B rows): thread=(d=t&31,k0=t>>5) ----
    {
        const int d = t & 31, k0 = t >> 5;
        const int rr = ph * 8 - 4 + k0;
        const int c0 = pw * 8 - 4;
        char* dst = smem + 34816 + d * 528 + k0 * 32;
        const __hip_bfloat16* src = xs + (size_t)(b * C2_ + C_ + h * 32 + d) * PIX_ + rr * 128 + c0;
        const bool rok = (unsigned)rr < 128u;
        if (rok && pw >= 1 && pw <= 14) {
            const uint2* s2 = (const uint2*)src;   // 8B aligned
            uint2 a0 = s2[0], a1 = s2[1], a2 = s2[2], a3 = s2[3];
            ((uint4*)dst)[0] = make_uint4(a0.x, a0.y, a1.x, a1.y);
            ((uint4*)dst)[1] = make_uint4(a2.x, a2.y, a3.x, a3.y);
        } else {
            __hip_bfloat16* dh = (__hip_bfloat16*)dst;
            __hip_bfloat16 z = __float2bfloat16(0.0f);
#pragma unroll
            for (int i = 0; i < 16; ++i) {
                bool ok = rok && ((unsigned)(c0 + i) < 128u);
                dh[i] = ok ? src[i] : z;
            }
        }
    }

    // ---- stage graph bits: gb[q][9] uints ----
    {
        unsigned int* gbl = (unsigned int*)(smem + 20480);
        const int q = t >> 3, wd = t & 7;
        gbl[q * 9 + wd] = gbits[(size_t)bg * 512 + t];
    }
    __syncthreads();   // sync1

    // ---- sim = Q K^T : 8 tiles of 16x16, K=32 in one MFMA each ----
    f32x4 acc[8];
    const f32x4 zz = {0.0f, 0.0f, 0.0f, 0.0f};
#pragma unroll
    for (int tile = 0; tile < 8; ++tile) {
        const short8v kb = *(const short8v*)(smem + (cb + tile * 16 + l15) * 80 + g * 16);
        acc[tile] = __builtin_amdgcn_mfma_f32_16x16x32_bf16(qa, kb, zz, 0, 0, 0);
    }

    // ---- mask + scale + row max ----
    const unsigned int* gbl = (const unsigned int*)(smem + 20480);
    float* redm = (float*)(smem + 51712);
    float* reds = (float*)(smem + 51712 + 512);
    float mx4[4], Mt[4], sm4[4], inv4[4];
#pragma unroll
    for (int j = 0; j < 4; ++j) {
        const int q = rbase + g * 4 + j;
        const unsigned int wv[4] = { gbl[q * 9 + cb32], gbl[q * 9 + cb32 + 1],
                                     gbl[q * 9 + cb32 + 2], gbl[q * 9 + cb32 + 3] };
        float mx = -3.0e38f;
#pragma unroll
        for (int tile = 0; tile < 8; ++tile) {
            unsigned int bit = (wv[tile >> 1] >> ((tile & 1) * 16 + l15)) & 1u;
            float s = acc[tile][j] * SCALE_ + (bit ? 0.0f : NEGM_);
            acc[tile][j] = s;
            mx = fmaxf(mx, s);
        }
        mx = fmaxf(mx, __shfl_xor(mx, 1));
        mx = fmaxf(mx, __shfl_xor(mx, 2));
        mx = fmaxf(mx, __shfl_xor(mx, 4));
        mx = fmaxf(mx, __shfl_xor(mx, 8));
        mx4[j] = mx;
        if (l15 == 0) redm[wcol * 64 + q] = mx;
    }
    __syncthreads();   // sync2
#pragma unroll
    for (int j = 0; j < 4; ++j) {
        const int q = rbase + g * 4 + j;
        Mt[j] = fmaxf(mx4[j], redm[(wcol ^ 1) * 64 + q]);
        float sm = 0.0f;
#pragma unroll
        for (int tile = 0; tile < 8; ++tile) {
            float e = __expf(acc[tile][j] - Mt[j]);
            acc[tile][j] = e;
            sm += e;
        }
        sm += __shfl_xor(sm, 1);
        sm += __shfl_xor(sm, 2);
        sm += __shfl_xor(sm, 4);
        sm += __shfl_xor(sm, 8);
        sm4[j] = sm;
        if (l15 == 0) reds[wcol * 64 + q] = sm;
    }
    __syncthreads();   // sync3
#pragma unroll
    for (int j = 0; j < 4; ++j) {
        const int q = rbase + g * 4 + j;
        inv4[j] = 1.0f / (sm4[j] + reds[(wcol ^ 1) * 64 + q]);
    }

    // ---- write P (bf16) to per-wave pl region ----
    char* plw = smem + w * 4352;
#pragma unroll
    for (int tile = 0; tile < 8; ++tile)
#pragma unroll
        for (int j = 0; j < 4; ++j) {
            *(__hip_bfloat16*)(plw + (g * 4 + j) * 272 + (tile * 16 + l15) * 2) =
                __float2bfloat16(acc[tile][j] * inv4[j]);
        }

    // ---- PV ----
    f32x4 o0 = zz, o1 = zz;
#pragma unroll
    for (int ks = 0; ks < 4; ++ks) {
        const short8v pa  = *(const short8v*)(plw + l15 * 272 + (ks * 32 + g * 8) * 2);
        const short8v vb0 = *(const short8v*)(smem + 34816 + l15 * 528        + (cb + ks * 32 + g * 8) * 2);
        const short8v vb1 = *(const short8v*)(smem + 34816 + (16 + l15) * 528 + (cb + ks * 32 + g * 8) * 2);
        o0 = __builtin_amdgcn_mfma_f32_16x16x32_bf16(pa, vb0, o0, 0, 0, 0);
        o1 = __builtin_amdgcn_mfma_f32_16x16x32_bf16(pa, vb1, o1, 0, 0, 0);
    }
    __syncthreads();   // sync4

    // ---- cross-half reduce + store ----
    float* ob = (float*)smem;   // [64][33] f32
    if (wcol == 1) {
#pragma unroll
        for (int j = 0; j < 4; ++j) {
            const int q = rbase + g * 4 + j;
            ob[q * 33 + l15]      = o0[j];
            ob[q * 33 + 16 + l15] = o1[j];
        }
    }
    __syncthreads();   // sync5
    if (wcol == 0) {
#pragma unroll
        for (int j = 0; j < 4; ++j) {
            const int q = rbase + g * 4 + j;
            float v0 = o0[j] + ob[q * 33 + l15];
            float v1 = o1[j] + ob[q * 33 + 16 + l15];
            attn[((size_t)bg * 64 + q) * 192 + h * 32 + l15]      = v0;
            attn[((size_t)bg * 64 + q) * 192 + h * 32 + 16 + l15] = v1;
        }
    }
}

// ---------------------------------------------------------------------------
// Kernel 4 (MFMA): final projection out = attn @ wp^T + bp, in-place on d_out.
// Block: 64 rows x 64 oc, K=192. Grid 3072 = 1024 row-tiles x 3 oc-tiles
// (oc fastest) with bijective XCD-chunk swizzle. A staged f32->bf16 in LDS
// (400B rows); B = wpb bf16 rows direct from global. Accumulators stored
// transposed ot[px][oc] (68-float rows) -> f32x4 epilogue reads + coalesced
// global writes. In-place safe: block reads only its own 64 rows, barrier,
// then writes them.
// ---------------------------------------------------------------------------
__global__ __launch_bounds__(256, 4)
void k_oprojm(const float* __restrict__ attn, const __hip_bfloat16* __restrict__ wpb,
              const float* __restrict__ bp, float* __restrict__ out)
{
    __shared__ __align__(16) char smem[25600];   // at [64r][400B] bf16 / ot f32 [64px][68]
    const int bid0 = blockIdx.x;
    const int bid = (bid0 & 7) * 384 + (bid0 >> 3);   // 3072 = 8 x 384, bijective
    const int oct = bid % 3;
    const int rt  = bid / 3;
    const int row0 = rt * 64;
    const int t = threadIdx.x;

    // ---- stage A: attn[row0..+64][192] f32 -> bf16 LDS (coalesced) ----
#pragma unroll
    for (int e0 = 0; e0 < 12; ++e0) {
        const int e = e0 * 256 + t;          // 3072 float4s
        const int r = e / 48, c4 = e % 48;
        float4 v = *(const float4*)(attn + (size_t)(row0 + r) * 192 + c4 * 4);
        union { uint2 u; __hip_bfloat16 h[4]; } pk;
        pk.h[0] = __float2bfloat16(v.x); pk.h[1] = __float2bfloat16(v.y);
        pk.h[2] = __float2bfloat16(v.z); pk.h[3] = __float2bfloat16(v.w);
        *(uint2*)(smem + r * 400 + c4 * 8) = pk.u;
    }
    __syncthreads();

    const int w = t >> 6, lane = t & 63;
    const int l15 = lane & 15, g = lane >> 4;
    const int mb = (w & 1) * 32;     // row quadrant
    const int nb = (w >> 1) * 32;    // oc quadrant

    const f32x4 zz = {0.0f, 0.0f, 0.0f, 0.0f};
    f32x4 acc00 = zz, acc01 = zz, acc10 = zz, acc11 = zz;
    const __hip_bfloat16* w0 = wpb + (size_t)(oct * 64 + nb + l15) * C_;
    const __hip_bfloat16* w1 = w0 + 16 * C_;
#pragma unroll
    for (int ks = 0; ks < 6; ++ks) {
        const short8v a0 = *(const short8v*)(smem + (mb + l15) * 400      + ks * 64 + g * 16);
        const short8v a1 = *(const short8v*)(smem + (mb + 16 + l15) * 400 + ks * 64 + g * 16);
        const short8v b0 = *(const short8v*)(w0 + ks * 32 + g * 8);
        const short8v b1 = *(const short8v*)(w1 + ks * 32 + g * 8);
        acc00 = __builtin_amdgcn_mfma_f32_16x16x32_bf16(a0, b0, acc00, 0, 0, 0);
        acc01 = __builtin_amdgcn_mfma_f32_16x16x32_bf16(a0, b1, acc01, 0, 0, 0);
        acc10 = __builtin_amdgcn_mfma_f32_16x16x32_bf16(a1, b0, acc10, 0, 0, 0);
        acc11 = __builtin_amdgcn_mfma_f32_16x16x32_bf16(a1, b1, acc11, 0, 0, 0);
    }
    __syncthreads();   // A-frag reads done -> overlay ot

    // ---- store transposed ot[px][oc] (68-float rows); scalar stores 2-way=free ----
    float* ot = (float*)smem;
#pragma unroll
    for (int j = 0; j < 4; ++j) {
        ot[(mb + g * 4 + j) * 68      + nb + l15]      = acc00[j];
        ot[(mb + 16 + g * 4 + j) * 68 + nb + l15]      = acc10[j];
        ot[(mb + g * 4 + j) * 68      + nb + 16 + l15] = acc01[j];
        ot[(mb + 16 + g * 4 + j) * 68 + nb + 16 + l15] = acc11[j];
    }
    __syncthreads();

    // ---- epilogue: bias + coalesced f32 write ----
    {
        const int k = t & 15, pxi = t >> 4;
        const float4 bias4 = *(const float4*)(bp + oct * 64 + k * 4);
#pragma unroll
        for (int p = 0; p < 4; ++p) {
            const int px = p * 16 + pxi;
            float4 v = *(const float4*)&ot[px * 68 + k * 4];
            v.x += bias4.x; v.y += bias4.y; v.z += bias4.z; v.w += bias4.w;
            *(float4*)(out + (size_t)(row0 + px) * 192 + oct * 64 + k * 4) = v;
        }
    }
}

// ---------------------------------------------------------------------------
extern "C" void kernel_launch(void* const* d_in, const int* in_sizes, int n_in,
                              void* d_out, int out_size, void* d_ws, size_t ws_size,
                              hipStream_t stream)
{
    (void)in_sizes; (void)n_in; (void)out_size; (void)ws_size;
    const float* x   = (const float*)d_in[0];
    const int* grph  = (const int*)d_in[1];     // jnp bool -> int32 per harness
    const float* wg  = (const float*)d_in[2];
    const float* bgb = (const float*)d_in[3];
    const float* wsm = (const float*)d_in[4];
    const float* bsm = (const float*)d_in[5];
    const float* wp  = (const float*)d_in[6];
    const float* bp  = (const float*)d_in[7];
    float* out = (float*)d_out;

    char* wsb = (char*)d_ws;
    __hip_bfloat16* xs  = (__hip_bfloat16*)wsb;                  // 50,331,648 B (conv out, bf16)
    __hip_bfloat16* qbf = (__hip_bfloat16*)(wsb + 50331648ull);  // 25,165,824 B (q bf16)
    float2* tbl = (float2*)(wsb + 75497472ull);                  // 32,768 B (rope table)
    unsigned int* gbits = (unsigned int*)(wsb + 75530240ull);    // 2,097,152 B (graph bits)
    __hip_bfloat16* wb  = (__hip_bfloat16*)(wsb + 77627392ull);  // 221,184 B (ws+wg bf16)
    __hip_bfloat16* wpb = wb + 110592;                           // 73,728 B (wp bf16)

    hipLaunchKernelGGL(k_rope_init, dim3(16),   dim3(256), 0, stream, tbl);
    hipLaunchKernelGGL(k_wcast,     dim3(144),  dim3(256), 0, stream, wsm, wg, wp, wb);
    hipLaunchKernelGGL(k_gmask,     dim3(2048), dim3(256), 0, stream, grph, gbits);
    hipLaunchKernelGGL(k_convm,     dim3(9216), dim3(256), 0, stream, x, wb, bsm, bgb, tbl, xs, qbf);
    hipLaunchKernelGGL(k_attn,      dim3(6144), dim3(512), 0, stream, xs, gbits, qbf, tbl, out);
    hipLaunchKernelGGL(k_oprojm,    dim3(3072), dim3(256), 0, stream, out, wpb, bp, out);
}

// Round 6
// 215.506 us; speedup vs baseline: 3.7363x; 1.0703x over previous
//
#include <hip/hip_runtime.h>
#include <hip/hip_bf16.h>

// Problem constants
#define B_    4
#define C_    192
#define C2_   384
#define PIX_  16384      // 128*128
#define NH_   6
#define BG_   1024
#define SCALE_ 0.17677669529663687f   // 32^-0.5
#define NEGM_ (-17.677669529663685f)  // -100 * SCALE_

typedef __attribute__((ext_vector_type(8))) short short8v;   // 8 bf16 = 4 VGPR
typedef __attribute__((ext_vector_type(4))) float f32x4;

// ---------------------------------------------------------------------------
// Kernel 0: RoPE cos/sin table
// ---------------------------------------------------------------------------
__global__ __launch_bounds__(256, 1)
void k_rope_init(float2* __restrict__ tbl) {
    int e = blockIdx.x * 256 + threadIdx.x;    // 4096 entries
    if (e >= 4096) return;
    int pos = e >> 4, j = e & 15;
    float freq = powf(10.0f, -0.25f * (float)j);
    float ang = (float)pos * freq;
    float sn, cs;
    sincosf(ang, &sn, &cs);
    tbl[e] = make_float2(cs, sn);
}

// ---------------------------------------------------------------------------
// Kernel 0b: graph int32 -> bitmask
// ---------------------------------------------------------------------------
__global__ __launch_bounds__(256, 4)
void k_gmask(const int* __restrict__ g, unsigned int* __restrict__ gbits) {
    int e = blockIdx.x * 256 + threadIdx.x;            // 524288 dwords
    const uint4* p = (const uint4*)(g + (size_t)e * 32);
    unsigned int m = 0u;
#pragma unroll
    for (int i = 0; i < 8; ++i) {
        uint4 v = p[i];
        m |= (v.x ? 1u : 0u) << (i * 4);
        m |= (v.y ? 1u : 0u) << (i * 4 + 1);
        m |= (v.z ? 1u : 0u) << (i * 4 + 2);
        m |= (v.w ? 1u : 0u) << (i * 4 + 3);
    }
    gbits[e] = m;
}

// ---------------------------------------------------------------------------
// Kernel 0c: cast w_sample ++ w_group ++ w_proj -> bf16
// ---------------------------------------------------------------------------
__global__ __launch_bounds__(256, 4)
void k_wcast(const float* __restrict__ wsm, const float* __restrict__ wgb,
             const float* __restrict__ wpj, __hip_bfloat16* __restrict__ wb)
{
    int e = (blockIdx.x * 256 + threadIdx.x) * 4;      // 147456 elems
    float4 v = (e < 73728) ? *(const float4*)(wsm + e)
             : (e < 110592) ? *(const float4*)(wgb + (e - 73728))
                            : *(const float4*)(wpj + (e - 110592));
    union { uint2 u; __hip_bfloat16 h[4]; } pk;
    pk.h[0] = __float2bfloat16(v.x); pk.h[1] = __float2bfloat16(v.y);
    pk.h[2] = __float2bfloat16(v.z); pk.h[3] = __float2bfloat16(v.w);
    *(uint2*)(wb + e) = pk.u;
}

// ---------------------------------------------------------------------------
// Kernel 1 (MFMA): fused 1x1 conv 192 -> 576.
// oct 0..2: K channels (x2 part, out-ch 0..191)  -> xsk [b][pix][192] TOKEN-major
// oct 3..5: V channels (feat part, 192..383)     -> xsv [b][192][pix] CHANNEL-major
// oct 6..8: q path: bias + RoPE(n) + l2norm      -> qbf [bg][h][n][32]
// Accumulator tile stored ot[oc][px] for the V branch (row writes per oc),
// ot[px][oc] (transposed) for K/q branches (row reads per pixel).
// ---------------------------------------------------------------------------
__global__ __launch_bounds__(256, 4)
void k_convm(const float* __restrict__ x, const __hip_bfloat16* __restrict__ wb,
             const float* __restrict__ bsm, const float* __restrict__ bgb,
             const float2* __restrict__ tbl,
             __hip_bfloat16* __restrict__ xsk, __hip_bfloat16* __restrict__ xsv,
             __hip_bfloat16* __restrict__ qbf)
{
    __shared__ __align__(16) char smem[25600];   // xt [64px][400B] / ot f32 [64][68]
    const int bid0 = blockIdx.x;
    const int bid = (bid0 & 7) * 1152 + (bid0 >> 3);   // 9216 = 8 x 1152, bijective
    const int oct = bid % 9;
    const int pb  = bid / 9;
    const int b = pb >> 8, pt = pb & 255;
    const int px0 = pt * 64;
    const int t = threadIdx.x;

    // ---- stage x tile [64 px][192 c] -> bf16 LDS, transposed ----
    {
        const int px = t & 63, cq = t >> 6;
        const float* src = x + ((size_t)b * C_ + cq * 48) * PIX_ + px0 + px;
        char* row = smem + px * 400 + cq * 96;
#pragma unroll
        for (int i = 0; i < 6; ++i) {
            union { uint4 u; __hip_bfloat16 h[8]; } pk;
#pragma unroll
            for (int j = 0; j < 8; ++j)
                pk.h[j] = __float2bfloat16(src[(size_t)(i * 8 + j) * PIX_]);
            *(uint4*)(row + i * 16) = pk.u;
        }
    }
    __syncthreads();

    const int w = t >> 6, lane = t & 63;
    const int l15 = lane & 15, g = lane >> 4;
    const int mb = (w & 1) * 32;     // px quadrant
    const int nb = (w >> 1) * 32;    // oc quadrant

    const f32x4 zz = {0.0f, 0.0f, 0.0f, 0.0f};
    f32x4 acc00 = zz, acc01 = zz, acc10 = zz, acc11 = zz;
    const __hip_bfloat16* w0 = wb + (size_t)(oct * 64 + nb + l15) * C_;
    const __hip_bfloat16* w1 = w0 + 16 * C_;
#pragma unroll
    for (int ks = 0; ks < 6; ++ks) {
        const short8v a0 = *(const short8v*)(smem + (mb + l15) * 400      + ks * 64 + g * 16);
        const short8v a1 = *(const short8v*)(smem + (mb + 16 + l15) * 400 + ks * 64 + g * 16);
        const short8v b0 = *(const short8v*)(w0 + ks * 32 + g * 8);
        const short8v b1 = *(const short8v*)(w1 + ks * 32 + g * 8);
        acc00 = __builtin_amdgcn_mfma_f32_16x16x32_bf16(a0, b0, acc00, 0, 0, 0);
        acc01 = __builtin_amdgcn_mfma_f32_16x16x32_bf16(a0, b1, acc01, 0, 0, 0);
        acc10 = __builtin_amdgcn_mfma_f32_16x16x32_bf16(a1, b0, acc10, 0, 0, 0);
        acc11 = __builtin_amdgcn_mfma_f32_16x16x32_bf16(a1, b1, acc11, 0, 0, 0);
    }
    __syncthreads();   // A-frag reads done -> overlay ot

    float* ot = (float*)smem;
    if (oct >= 3 && oct < 6) {
        // ---- V branch: ot[oc][px], channel-major write (unchanged path) ----
        *(f32x4*)&ot[(nb + l15) * 68      + mb + g * 4]      = acc00;
        *(f32x4*)&ot[(nb + l15) * 68      + mb + 16 + g * 4] = acc10;
        *(f32x4*)&ot[(nb + 16 + l15) * 68 + mb + g * 4]      = acc01;
        *(f32x4*)&ot[(nb + 16 + l15) * 68 + mb + 16 + g * 4] = acc11;
        __syncthreads();
        const float* bias = bsm + oct * 64;
#pragma unroll
        for (int e0 = 0; e0 < 2; ++e0) {
            const int e = e0 * 256 + t;
            const int oc = e >> 3, seg = e & 7;
            const float bo = bias[oc];
            float4 v0 = *(const float4*)&ot[oc * 68 + seg * 8];
            float4 v1 = *(const float4*)&ot[oc * 68 + seg * 8 + 4];
            union { uint4 u; __hip_bfloat16 h[8]; } pk;
            pk.h[0] = __float2bfloat16(v0.x + bo); pk.h[1] = __float2bfloat16(v0.y + bo);
            pk.h[2] = __float2bfloat16(v0.z + bo); pk.h[3] = __float2bfloat16(v0.w + bo);
            pk.h[4] = __float2bfloat16(v1.x + bo); pk.h[5] = __float2bfloat16(v1.y + bo);
            pk.h[6] = __float2bfloat16(v1.z + bo); pk.h[7] = __float2bfloat16(v1.w + bo);
            *(uint4*)(xsv + (size_t)(b * C_ + (oct - 3) * 64 + oc) * PIX_ + px0 + seg * 8) = pk.u;
        }
    } else {
        // ---- K / q branches: transposed ot[px][oc] (68-float rows) ----
#pragma unroll
        for (int j = 0; j < 4; ++j) {
            ot[(mb + g * 4 + j) * 68      + nb + l15]      = acc00[j];
            ot[(mb + 16 + g * 4 + j) * 68 + nb + l15]      = acc10[j];
            ot[(mb + g * 4 + j) * 68      + nb + 16 + l15] = acc01[j];
            ot[(mb + 16 + g * 4 + j) * 68 + nb + 16 + l15] = acc11[j];
        }
        __syncthreads();
        if (oct < 3) {
            // token-major K write: thread = (px = t>>2, i = t&3), 32B each
            const int px = t >> 2, i = t & 3;
            const int ocb = oct * 64 + i * 16;
            union { uint4 u[2]; __hip_bfloat16 h[16]; } pk;
#pragma unroll
            for (int q4 = 0; q4 < 4; ++q4) {
                float4 v  = *(const float4*)&ot[px * 68 + i * 16 + q4 * 4];
                float4 bv = *(const float4*)(bsm + ocb + q4 * 4);
                pk.h[q4 * 4 + 0] = __float2bfloat16(v.x + bv.x);
                pk.h[q4 * 4 + 1] = __float2bfloat16(v.y + bv.y);
                pk.h[q4 * 4 + 2] = __float2bfloat16(v.z + bv.z);
                pk.h[q4 * 4 + 3] = __float2bfloat16(v.w + bv.w);
            }
            __hip_bfloat16* dst = xsk + ((size_t)b * PIX_ + px0 + px) * C_ + ocb;
            *(uint4*)dst       = pk.u[0];
            *(uint4*)(dst + 8) = pk.u[1];
        } else {
            // q path: bias + RoPE + l2norm per (pixel, head); 2 heads in tile
            const int px = t & 63, hh = t >> 6;
            if (hh < 2) {
                const int p = px0 + px;
                const int r = p >> 7, c = p & 127;
                const int n = (r & 7) * 8 + (c & 7);
                const int bg = (b << 8) + ((r >> 3) << 4) + (c >> 3);
                const int hglob = (oct - 6) * 2 + hh;
                float v[32];
#pragma unroll
                for (int d4 = 0; d4 < 8; ++d4) {
                    float4 vv = *(const float4*)&ot[px * 68 + hh * 32 + d4 * 4];
                    float4 bv = *(const float4*)(bgb + hglob * 32 + d4 * 4);
                    v[d4 * 4 + 0] = vv.x + bv.x; v[d4 * 4 + 1] = vv.y + bv.y;
                    v[d4 * 4 + 2] = vv.z + bv.z; v[d4 * 4 + 3] = vv.w + bv.w;
                }
                float rr[32];
#pragma unroll
                for (int j = 0; j < 16; ++j) {
                    float2 cs = tbl[n * 16 + j];
                    float a0 = v[2 * j], a1 = v[2 * j + 1];
                    rr[2 * j]     = a0 * cs.x - a1 * cs.y;
                    rr[2 * j + 1] = a1 * cs.x + a0 * cs.y;
                }
                float n2 = 0.0f;
#pragma unroll
                for (int d = 0; d < 32; ++d) n2 = fmaf(rr[d], rr[d], n2);
                const float inv = 1.0f / fmaxf(sqrtf(n2), 1e-12f);
                __hip_bfloat16* dst = qbf + ((size_t)(bg * NH_ + hglob) * 64 + n) * 32;
#pragma unroll
                for (int c8 = 0; c8 < 4; ++c8) {
                    union { uint4 u; __hip_bfloat16 h[8]; } pk;
#pragma unroll
                    for (int i = 0; i < 8; ++i) pk.h[i] = __float2bfloat16(rr[c8 * 8 + i] * inv);
                    *(uint4*)(dst + c8 * 8) = pk.u;
                }
            }
        }
    }
}

// ---------------------------------------------------------------------------
// Kernel 3 (MFMA): attention for one (bg, head). K from token-major xsk
// (2x dwordx4 per thread), V from channel-major xsv (unchanged). XCD-chunk
// swizzle: each XCD owns 128 consecutive windows (all 6 heads + overlapping
// neighbors share its L2).
// ---------------------------------------------------------------------------
__global__ __launch_bounds__(512, 2)
void k_attn(const __hip_bfloat16* __restrict__ xsk, const __hip_bfloat16* __restrict__ xsv,
            const unsigned int* __restrict__ gbits, const __hip_bfloat16* __restrict__ qb,
            const float2* __restrict__ tbl, float* __restrict__ attn)
{
    __shared__ __align__(16) char smem[52736];
    const int bid0 = blockIdx.x;
    const int bid = (bid0 & 7) * 768 + (bid0 >> 3);    // 6144 = 8 x 768, bijective
    const int h = bid % NH_;
    const int bg = bid / NH_;
    const int b = bg >> 8, ph = (bg >> 4) & 15, pw = bg & 15;
    const int t = threadIdx.x;
    const int w = t >> 6, lane = t & 63;
    const int g = lane >> 4, l15 = lane & 15;
    const int rbase = (w & 3) * 16;        // q rows
    const int wcol  = w >> 2;              // kv half
    const int cb    = wcol * 128;
    const int cb32  = wcol * 4;

    // ---- A-frag: Q direct from global (issue early) ----
    const short8v qa = *(const short8v*)(qb +
        ((size_t)(bg * NH_ + h) * 64 + rbase + l15) * 32 + g * 8);

    // ---- stage K (rope+norm, bf16) into kl: thread=(m=t>>1, half=t&1) ----
    {
        const int m = t >> 1, half = t & 1;
        const int k0 = m >> 4, k1 = m & 15;
        const int rr = ph * 8 - 4 + k0, cc = pw * 8 - 4 + k1;
        const bool inb = ((unsigned)rr < 128u) && ((unsigned)cc < 128u);
        float kv[16];
        if (inb) {
            const uint4* pk = (const uint4*)(xsk +
                ((size_t)b * PIX_ + rr * 128 + cc) * C_ + h * 32 + half * 16);
            union { uint4 u; __hip_bfloat16 h8[8]; } r0, r1;
            r0.u = pk[0]; r1.u = pk[1];
#pragma unroll
            for (int d = 0; d < 8; ++d) {
                kv[d]     = __bfloat162float(r0.h8[d]);
                kv[8 + d] = __bfloat162float(r1.h8[d]);
            }
        } else {
#pragma unroll
            for (int d = 0; d < 16; ++d) kv[d] = 0.0f;
        }
#pragma unroll
        for (int p = 0; p < 8; ++p) {
            float2 cs = tbl[m * 16 + half * 8 + p];
            float a0 = kv[2 * p], a1 = kv[2 * p + 1];
            kv[2 * p]     = a0 * cs.x - a1 * cs.y;
            kv[2 * p + 1] = a1 * cs.x + a0 * cs.y;
        }
        float n2 = 0.0f;
#pragma unroll
        for (int d = 0; d < 16; ++d) n2 = fmaf(kv[d], kv[d], n2);
        n2 += __shfl_xor(n2, 1);
        const float inv = 1.0f / fmaxf(sqrtf(n2), 1e-12f);
        union { uint4 u; __hip_bfloat16 hh[8]; } p0, p1;
#pragma unroll
        for (int i = 0; i < 8; ++i) {
            p0.hh[i] = __float2bfloat16(kv[i] * inv);
            p1.hh[i] = __float2bfloat16(kv[8 + i] * inv);
        }
        *(uint4*)(smem + m * 80 + half * 32)      = p0.u;
        *(uint4*)(smem + m * 80 + half * 32 + 16) = p1.u;
    }

    // ---- stage V transposed into vl[d][kv] (528B rows): thread=(d=t&31,k0=t>>5) ----
    {
        const int d = t & 31, k0 = t >> 5;
        const int rr = ph * 8 - 4 + k0;
        const int c0 = pw * 8 - 4;
        char* dst = smem + 34816 + d * 528 + k0 * 32;
        const __hip_bfloat16* src = xsv + (size_t)(b * C_ + h * 32 + d) * PIX_ + rr * 128 + c0;
        const bool rok = (unsigned)rr < 128u;
        if (rok && pw >= 1 && pw <= 14) {
            const uint2* s2 = (const uint2*)src;   // 8B aligned
            uint2 a0 = s2[0], a1 = s2[1], a2 = s2[2], a3 = s2[3];
            ((uint4*)dst)[0] = make_uint4(a0.x, a0.y, a1.x, a1.y);
            ((uint4*)dst)[1] = make_uint4(a2.x, a2.y, a3.x, a3.y);
        } else {
            __hip_bfloat16* dh = (__hip_bfloat16*)dst;
            __hip_bfloat16 z = __float2bfloat16(0.0f);
#pragma unroll
            for (int i = 0; i < 16; ++i) {
                bool ok = rok && ((unsigned)(c0 + i) < 128u);
                dh[i] = ok ? src[i] : z;
            }
        }
    }

    // ---- stage graph bits: gb[q][9] uints ----
    {
        unsigned int* gbl = (unsigned int*)(smem + 20480);
        const int q = t >> 3, wd = t & 7;
        gbl[q * 9 + wd] = gbits[(size_t)bg * 512 + t];
    }
    __syncthreads();   // sync1

    // ---- sim = Q K^T : 8 tiles of 16x16, K=32 in one MFMA each ----
    f32x4 acc[8];
    const f32x4 zz = {0.0f, 0.0f, 0.0f, 0.0f};
#pragma unroll
    for (int tile = 0; tile < 8; ++tile) {
        const short8v kb = *(const short8v*)(smem + (cb + tile * 16 + l15) * 80 + g * 16);
        acc[tile] = __builtin_amdgcn_mfma_f32_16x16x32_bf16(qa, kb, zz, 0, 0, 0);
    }

    // ---- mask + scale + row max ----
    const unsigned int* gbl = (const unsigned int*)(smem + 20480);
    float* redm = (float*)(smem + 51712);
    float* reds = (float*)(smem + 51712 + 512);
    float mx4[4], Mt[4], sm4[4], inv4[4];
#pragma unroll
    for (int j = 0; j < 4; ++j) {
        const int q = rbase + g * 4 + j;
        const unsigned int wv[4] = { gbl[q * 9 + cb32], gbl[q * 9 + cb32 + 1],
                                     gbl[q * 9 + cb32 + 2], gbl[q * 9 + cb32 + 3] };
        float mx = -3.0e38f;
#pragma unroll
        for (int tile = 0; tile < 8; ++tile) {
            unsigned int bit = (wv[tile >> 1] >> ((tile & 1) * 16 + l15)) & 1u;
            float s = acc[tile][j] * SCALE_ + (bit ? 0.0f : NEGM_);
            acc[tile][j] = s;
            mx = fmaxf(mx, s);
        }
        mx = fmaxf(mx, __shfl_xor(mx, 1));
        mx = fmaxf(mx, __shfl_xor(mx, 2));
        mx = fmaxf(mx, __shfl_xor(mx, 4));
        mx = fmaxf(mx, __shfl_xor(mx, 8));
        mx4[j] = mx;
        if (l15 == 0) redm[wcol * 64 + q] = mx;
    }
    __syncthreads();   // sync2
#pragma unroll
    for (int j = 0; j < 4; ++j) {
        const int q = rbase + g * 4 + j;
        Mt[j] = fmaxf(mx4[j], redm[(wcol ^ 1) * 64 + q]);
        float sm = 0.0f;
#pragma unroll
        for (int tile = 0; tile < 8; ++tile) {
            float e = __expf(acc[tile][j] - Mt[j]);
            acc[tile][j] = e;
            sm += e;
        }
        sm += __shfl_xor(sm, 1);
        sm += __shfl_xor(sm, 2);
        sm += __shfl_xor(sm, 4);
        sm += __shfl_xor(sm, 8);
        sm4[j] = sm;
        if (l15 == 0) reds[wcol * 64 + q] = sm;
    }
    __syncthreads();   // sync3
#pragma unroll
    for (int j = 0; j < 4; ++j) {
        const int q = rbase + g * 4 + j;
        inv4[j] = 1.0f / (sm4[j] + reds[(wcol ^ 1) * 64 + q]);
    }

    // ---- write P (bf16) to per-wave pl region ----
    char* plw = smem + w * 4352;
#pragma unroll
    for (int tile = 0; tile < 8; ++tile)
#pragma unroll
        for (int j = 0; j < 4; ++j) {
            *(__hip_bfloat16*)(plw + (g * 4 + j) * 272 + (tile * 16 + l15) * 2) =
                __float2bfloat16(acc[tile][j] * inv4[j]);
        }

    // ---- PV ----
    f32x4 o0 = zz, o1 = zz;
#pragma unroll
    for (int ks = 0; ks < 4; ++ks) {
        const short8v pa  = *(const short8v*)(plw + l15 * 272 + (ks * 32 + g * 8) * 2);
        const short8v vb0 = *(const short8v*)(smem + 34816 + l15 * 528        + (cb + ks * 32 + g * 8) * 2);
        const short8v vb1 = *(const short8v*)(smem + 34816 + (16 + l15) * 528 + (cb + ks * 32 + g * 8) * 2);
        o0 = __builtin_amdgcn_mfma_f32_16x16x32_bf16(pa, vb0, o0, 0, 0, 0);
        o1 = __builtin_amdgcn_mfma_f32_16x16x32_bf16(pa, vb1, o1, 0, 0, 0);
    }
    __syncthreads();   // sync4

    // ---- cross-half reduce + store ----
    float* ob = (float*)smem;   // [64][33] f32
    if (wcol == 1) {
#pragma unroll
        for (int j = 0; j < 4; ++j) {
            const int q = rbase + g * 4 + j;
            ob[q * 33 + l15]      = o0[j];
            ob[q * 33 + 16 + l15] = o1[j];
        }
    }
    __syncthreads();   // sync5
    if (wcol == 0) {
#pragma unroll
        for (int j = 0; j < 4; ++j) {
            const int q = rbase + g * 4 + j;
            float v0 = o0[j] + ob[q * 33 + l15];
            float v1 = o1[j] + ob[q * 33 + 16 + l15];
            attn[((size_t)bg * 64 + q) * 192 + h * 32 + l15]      = v0;
            attn[((size_t)bg * 64 + q) * 192 + h * 32 + 16 + l15] = v1;
        }
    }
}

// ---------------------------------------------------------------------------
// Kernel 4 (MFMA): final projection out = attn @ wp^T + bp, in-place on d_out.
// ---------------------------------------------------------------------------
__global__ __launch_bounds__(256, 4)
void k_oprojm(const float* __restrict__ attn, const __hip_bfloat16* __restrict__ wpb,
              const float* __restrict__ bp, float* __restrict__ out)
{
    __shared__ __align__(16) char smem[25600];   // at [64r][400B] bf16 / ot f32 [64px][68]
    const int bid0 = blockIdx.x;
    const int bid = (bid0 & 7) * 384 + (bid0 >> 3);   // 3072 = 8 x 384, bijective
    const int oct = bid % 3;
    const int rt  = bid / 3;
    const int row0 = rt * 64;
    const int t = threadIdx.x;

    // ---- stage A: attn[row0..+64][192] f32 -> bf16 LDS (coalesced) ----
#pragma unroll
    for (int e0 = 0; e0 < 12; ++e0) {
        const int e = e0 * 256 + t;          // 3072 float4s
        const int r = e / 48, c4 = e % 48;
        float4 v = *(const float4*)(attn + (size_t)(row0 + r) * 192 + c4 * 4);
        union { uint2 u; __hip_bfloat16 h[4]; } pk;
        pk.h[0] = __float2bfloat16(v.x); pk.h[1] = __float2bfloat16(v.y);
        pk.h[2] = __float2bfloat16(v.z); pk.h[3] = __float2bfloat16(v.w);
        *(uint2*)(smem + r * 400 + c4 * 8) = pk.u;
    }
    __syncthreads();

    const int w = t >> 6, lane = t & 63;
    const int l15 = lane & 15, g = lane >> 4;
    const int mb = (w & 1) * 32;     // row quadrant
    const int nb = (w >> 1) * 32;    // oc quadrant

    const f32x4 zz = {0.0f, 0.0f, 0.0f, 0.0f};
    f32x4 acc00 = zz, acc01 = zz, acc10 = zz, acc11 = zz;
    const __hip_bfloat16* w0 = wpb + (size_t)(oct * 64 + nb + l15) * C_;
    const __hip_bfloat16* w1 = w0 + 16 * C_;
#pragma unroll
    for (int ks = 0; ks < 6; ++ks) {
        const short8v a0 = *(const short8v*)(smem + (mb + l15) * 400      + ks * 64 + g * 16);
        const short8v a1 = *(const short8v*)(smem + (mb + 16 + l15) * 400 + ks * 64 + g * 16);
        const short8v b0 = *(const short8v*)(w0 + ks * 32 + g * 8);
        const short8v b1 = *(const short8v*)(w1 + ks * 32 + g * 8);
        acc00 = __builtin_amdgcn_mfma_f32_16x16x32_bf16(a0, b0, acc00, 0, 0, 0);
        acc01 = __builtin_amdgcn_mfma_f32_16x16x32_bf16(a0, b1, acc01, 0, 0, 0);
        acc10 = __builtin_amdgcn_mfma_f32_16x16x32_bf16(a1, b0, acc10, 0, 0, 0);
        acc11 = __builtin_amdgcn_mfma_f32_16x16x32_bf16(a1, b1, acc11, 0, 0, 0);
    }
    __syncthreads();   // A-frag reads done -> overlay ot

    // ---- store transposed ot[px][oc] (68-float rows) ----
    float* ot = (float*)smem;
#pragma unroll
    for (int j = 0; j < 4; ++j) {
        ot[(mb + g * 4 + j) * 68      + nb + l15]      = acc00[j];
        ot[(mb + 16 + g * 4 + j) * 68 + nb + l15]      = acc10[j];
        ot[(mb + g * 4 + j) * 68      + nb + 16 + l15] = acc01[j];
        ot[(mb + 16 + g * 4 + j) * 68 + nb + 16 + l15] = acc11[j];
    }
    __syncthreads();

    // ---- epilogue: bias + coalesced f32 write ----
    {
        const int k = t & 15, pxi = t >> 4;
        const float4 bias4 = *(const float4*)(bp + oct * 64 + k * 4);
#pragma unroll
        for (int p = 0; p < 4; ++p) {
            const int px = p * 16 + pxi;
            float4 v = *(const float4*)&ot[px * 68 + k * 4];
            v.x += bias4.x; v.y += bias4.y; v.z += bias4.z; v.w += bias4.w;
            *(float4*)(out + (size_t)(row0 + px) * 192 + oct * 64 + k * 4) = v;
        }
    }
}

// ---------------------------------------------------------------------------
extern "C" void kernel_launch(void* const* d_in, const int* in_sizes, int n_in,
                              void* d_out, int out_size, void* d_ws, size_t ws_size,
                              hipStream_t stream)
{
    (void)in_sizes; (void)n_in; (void)out_size; (void)ws_size;
    const float* x   = (const float*)d_in[0];
    const int* grph  = (const int*)d_in[1];     // jnp bool -> int32 per harness
    const float* wg  = (const float*)d_in[2];
    const float* bgb = (const float*)d_in[3];
    const float* wsm = (const float*)d_in[4];
    const float* bsm = (const float*)d_in[5];
    const float* wp  = (const float*)d_in[6];
    const float* bp  = (const float*)d_in[7];
    float* out = (float*)d_out;

    char* wsb = (char*)d_ws;
    __hip_bfloat16* xsk = (__hip_bfloat16*)wsb;                  // 25,165,824 B (K token-major)
    __hip_bfloat16* xsv = (__hip_bfloat16*)(wsb + 25165824ull);  // 25,165,824 B (V channel-major)
    __hip_bfloat16* qbf = (__hip_bfloat16*)(wsb + 50331648ull);  // 25,165,824 B (q bf16)
    float2* tbl = (float2*)(wsb + 75497472ull);                  // 32,768 B (rope table)
    unsigned int* gbits = (unsigned int*)(wsb + 75530240ull);    // 2,097,152 B (graph bits)
    __hip_bfloat16* wb  = (__hip_bfloat16*)(wsb + 77627392ull);  // 221,184 B (ws+wg bf16)
    __hip_bfloat16* wpb = wb + 110592;                           // 73,728 B (wp bf16)

    hipLaunchKernelGGL(k_rope_init, dim3(16),   dim3(256), 0, stream, tbl);
    hipLaunchKernelGGL(k_wcast,     dim3(144),  dim3(256), 0, stream, wsm, wg, wp, wb);
    hipLaunchKernelGGL(k_gmask,     dim3(2048), dim3(256), 0, stream, grph, gbits);
    hipLaunchKernelGGL(k_convm,     dim3(9216), dim3(256), 0, stream, x, wb, bsm, bgb, tbl, xsk, xsv, qbf);
    hipLaunchKernelGGL(k_attn,      dim3(6144), dim3(512), 0, stream, xsk, xsv, gbits, qbf, tbl, out);
    hipLaunchKernelGGL(k_oprojm,    dim3(3072), dim3(256), 0, stream, out, wpb, bp, out);
}

// Round 7
// 207.882 us; speedup vs baseline: 3.8734x; 1.0367x over previous
//
#include <hip/hip_runtime.h>
#include <hip/hip_bf16.h>

// Problem constants
#define B_    4
#define C_    192
#define C2_   384
#define PIX_  16384      // 128*128
#define NH_   6
#define BG_   1024
#define SCALE_ 0.17677669529663687f   // 32^-0.5
#define NEGM_ (-17.677669529663685f)  // -100 * SCALE_

typedef __attribute__((ext_vector_type(8))) short short8v;   // 8 bf16 = 4 VGPR
typedef __attribute__((ext_vector_type(4))) float f32x4;

// ---------------------------------------------------------------------------
// Kernel 0: RoPE cos/sin table
// ---------------------------------------------------------------------------
__global__ __launch_bounds__(256, 1)
void k_rope_init(float2* __restrict__ tbl) {
    int e = blockIdx.x * 256 + threadIdx.x;    // 4096 entries
    if (e >= 4096) return;
    int pos = e >> 4, j = e & 15;
    float freq = powf(10.0f, -0.25f * (float)j);
    float ang = (float)pos * freq;
    float sn, cs;
    sincosf(ang, &sn, &cs);
    tbl[e] = make_float2(cs, sn);
}

// ---------------------------------------------------------------------------
// Kernel 0b: graph int32 -> bitmask
// ---------------------------------------------------------------------------
__global__ __launch_bounds__(256, 4)
void k_gmask(const int* __restrict__ g, unsigned int* __restrict__ gbits) {
    int e = blockIdx.x * 256 + threadIdx.x;            // 524288 dwords
    const uint4* p = (const uint4*)(g + (size_t)e * 32);
    unsigned int m = 0u;
#pragma unroll
    for (int i = 0; i < 8; ++i) {
        uint4 v = p[i];
        m |= (v.x ? 1u : 0u) << (i * 4);
        m |= (v.y ? 1u : 0u) << (i * 4 + 1);
        m |= (v.z ? 1u : 0u) << (i * 4 + 2);
        m |= (v.w ? 1u : 0u) << (i * 4 + 3);
    }
    gbits[e] = m;
}

// ---------------------------------------------------------------------------
// Kernel 0c: cast w_sample ++ w_group ++ w_proj -> bf16
// ---------------------------------------------------------------------------
__global__ __launch_bounds__(256, 4)
void k_wcast(const float* __restrict__ wsm, const float* __restrict__ wgb,
             const float* __restrict__ wpj, __hip_bfloat16* __restrict__ wb)
{
    int e = (blockIdx.x * 256 + threadIdx.x) * 4;      // 147456 elems
    float4 v = (e < 73728) ? *(const float4*)(wsm + e)
             : (e < 110592) ? *(const float4*)(wgb + (e - 73728))
                            : *(const float4*)(wpj + (e - 110592));
    union { uint2 u; __hip_bfloat16 h[4]; } pk;
    pk.h[0] = __float2bfloat16(v.x); pk.h[1] = __float2bfloat16(v.y);
    pk.h[2] = __float2bfloat16(v.z); pk.h[3] = __float2bfloat16(v.w);
    *(uint2*)(wb + e) = pk.u;
}

// ---------------------------------------------------------------------------
// Kernel 1 (MFMA): fused 1x1 conv 192 -> 576, ONE block per 64-px tile.
// Stage x once, hoist A-frags to regs (xt LDS freed -> ot overlays), then
// loop 9 oct-tiles: B-frags from L2 + 24 MFMA/wave + per-branch epilogue.
// oct 0..2: K -> xsk [b][pix][192] token-major, bias + L2-NORMALIZED
//           (rope is a rotation -> norm is rope-invariant; attn skips norm)
// oct 3..5: V -> xsv [b][192][pix] channel-major, bias
// oct 6..8: q -> bias + RoPE(n) + l2norm -> qbf [bg][h][n][32]
// ---------------------------------------------------------------------------
__global__ __launch_bounds__(256, 4)
void k_convm(const float* __restrict__ x, const __hip_bfloat16* __restrict__ wb,
             const float* __restrict__ bsm, const float* __restrict__ bgb,
             const float2* __restrict__ tbl,
             __hip_bfloat16* __restrict__ xsk, __hip_bfloat16* __restrict__ xsv,
             __hip_bfloat16* __restrict__ qbf)
{
    __shared__ __align__(16) char smem[25600];   // xt [64px][400B] -> ot f32 [64][68]
    const int bid = blockIdx.x;                  // 1024 = b(4) x pt(256)
    const int b = bid >> 8, pt = bid & 255;
    const int px0 = pt * 64;
    const int t = threadIdx.x;

    // ---- stage x tile [64 px][192 c] -> bf16 LDS, transposed (once) ----
    {
        const int px = t & 63, cq = t >> 6;
        const float* src = x + ((size_t)b * C_ + cq * 48) * PIX_ + px0 + px;
        char* row = smem + px * 400 + cq * 96;
#pragma unroll
        for (int i = 0; i < 6; ++i) {
            union { uint4 u; __hip_bfloat16 h[8]; } pk;
#pragma unroll
            for (int j = 0; j < 8; ++j)
                pk.h[j] = __float2bfloat16(src[(size_t)(i * 8 + j) * PIX_]);
            *(uint4*)(row + i * 16) = pk.u;
        }
    }
    __syncthreads();

    const int w = t >> 6, lane = t & 63;
    const int l15 = lane & 15, g = lane >> 4;
    const int mb = (w & 1) * 32;     // px quadrant
    const int nb = (w >> 1) * 32;    // oc quadrant

    // ---- hoist A-frags to registers (same for all 9 octs) ----
    short8v a0r[6], a1r[6];
#pragma unroll
    for (int ks = 0; ks < 6; ++ks) {
        a0r[ks] = *(const short8v*)(smem + (mb + l15) * 400      + ks * 64 + g * 16);
        a1r[ks] = *(const short8v*)(smem + (mb + 16 + l15) * 400 + ks * 64 + g * 16);
    }
    __syncthreads();   // xt dead -> ot overlays

    float* ot = (float*)smem;
    const f32x4 zz = {0.0f, 0.0f, 0.0f, 0.0f};

    for (int oct = 0; oct < 9; ++oct) {
        f32x4 acc00 = zz, acc01 = zz, acc10 = zz, acc11 = zz;
        const __hip_bfloat16* w0 = wb + (size_t)(oct * 64 + nb + l15) * C_;
        const __hip_bfloat16* w1 = w0 + 16 * C_;
#pragma unroll
        for (int ks = 0; ks < 6; ++ks) {
            const short8v b0 = *(const short8v*)(w0 + ks * 32 + g * 8);
            const short8v b1 = *(const short8v*)(w1 + ks * 32 + g * 8);
            acc00 = __builtin_amdgcn_mfma_f32_16x16x32_bf16(a0r[ks], b0, acc00, 0, 0, 0);
            acc01 = __builtin_amdgcn_mfma_f32_16x16x32_bf16(a0r[ks], b1, acc01, 0, 0, 0);
            acc10 = __builtin_amdgcn_mfma_f32_16x16x32_bf16(a1r[ks], b0, acc10, 0, 0, 0);
            acc11 = __builtin_amdgcn_mfma_f32_16x16x32_bf16(a1r[ks], b1, acc11, 0, 0, 0);
        }
        __syncthreads();   // previous epilogue's ot reads done

        if (oct >= 3 && oct < 6) {
            // V branch: ot[oc][px]
            *(f32x4*)&ot[(nb + l15) * 68      + mb + g * 4]      = acc00;
            *(f32x4*)&ot[(nb + l15) * 68      + mb + 16 + g * 4] = acc10;
            *(f32x4*)&ot[(nb + 16 + l15) * 68 + mb + g * 4]      = acc01;
            *(f32x4*)&ot[(nb + 16 + l15) * 68 + mb + 16 + g * 4] = acc11;
        } else {
            // K / q branches: transposed ot[px][oc]
#pragma unroll
            for (int j = 0; j < 4; ++j) {
                ot[(mb + g * 4 + j) * 68      + nb + l15]      = acc00[j];
                ot[(mb + 16 + g * 4 + j) * 68 + nb + l15]      = acc10[j];
                ot[(mb + g * 4 + j) * 68      + nb + 16 + l15] = acc01[j];
                ot[(mb + 16 + g * 4 + j) * 68 + nb + 16 + l15] = acc11[j];
            }
        }
        __syncthreads();

        if (oct < 3) {
            // K: bias + l2norm (per head = 2 threads), token-major write
            const int px = t >> 2, i = t & 3;
            const int ocb = oct * 64 + i * 16;
            float v[16];
#pragma unroll
            for (int q4 = 0; q4 < 4; ++q4) {
                float4 vv = *(const float4*)&ot[px * 68 + i * 16 + q4 * 4];
                float4 bv = *(const float4*)(bsm + ocb + q4 * 4);
                v[q4 * 4 + 0] = vv.x + bv.x; v[q4 * 4 + 1] = vv.y + bv.y;
                v[q4 * 4 + 2] = vv.z + bv.z; v[q4 * 4 + 3] = vv.w + bv.w;
            }
            float n2 = 0.0f;
#pragma unroll
            for (int d = 0; d < 16; ++d) n2 = fmaf(v[d], v[d], n2);
            n2 += __shfl_xor(n2, 1);             // partner half of same head
            const float inv = 1.0f / fmaxf(sqrtf(n2), 1e-12f);
            union { uint4 u[2]; __hip_bfloat16 h[16]; } pk;
#pragma unroll
            for (int d = 0; d < 16; ++d) pk.h[d] = __float2bfloat16(v[d] * inv);
            __hip_bfloat16* dst = xsk + ((size_t)b * PIX_ + px0 + px) * C_ + ocb;
            *(uint4*)dst       = pk.u[0];
            *(uint4*)(dst + 8) = pk.u[1];
        } else if (oct < 6) {
            // V: bias, channel-major write
            const float* bias = bsm + oct * 64;
#pragma unroll
            for (int e0 = 0; e0 < 2; ++e0) {
                const int e = e0 * 256 + t;
                const int oc = e >> 3, seg = e & 7;
                const float bo = bias[oc];
                float4 v0 = *(const float4*)&ot[oc * 68 + seg * 8];
                float4 v1 = *(const float4*)&ot[oc * 68 + seg * 8 + 4];
                union { uint4 u; __hip_bfloat16 h[8]; } pk;
                pk.h[0] = __float2bfloat16(v0.x + bo); pk.h[1] = __float2bfloat16(v0.y + bo);
                pk.h[2] = __float2bfloat16(v0.z + bo); pk.h[3] = __float2bfloat16(v0.w + bo);
                pk.h[4] = __float2bfloat16(v1.x + bo); pk.h[5] = __float2bfloat16(v1.y + bo);
                pk.h[6] = __float2bfloat16(v1.z + bo); pk.h[7] = __float2bfloat16(v1.w + bo);
                *(uint4*)(xsv + (size_t)(b * C_ + (oct - 3) * 64 + oc) * PIX_ + px0 + seg * 8) = pk.u;
            }
        } else {
            // q: bias + RoPE + l2norm; 2 heads in this tile
            const int px = t & 63, hh = t >> 6;
            if (hh < 2) {
                const int p = px0 + px;
                const int r = p >> 7, c = p & 127;
                const int n = (r & 7) * 8 + (c & 7);
                const int bg = (b << 8) + ((r >> 3) << 4) + (c >> 3);
                const int hglob = (oct - 6) * 2 + hh;
                float v[32];
#pragma unroll
                for (int d4 = 0; d4 < 8; ++d4) {
                    float4 vv = *(const float4*)&ot[px * 68 + hh * 32 + d4 * 4];
                    float4 bv = *(const float4*)(bgb + hglob * 32 + d4 * 4);
                    v[d4 * 4 + 0] = vv.x + bv.x; v[d4 * 4 + 1] = vv.y + bv.y;
                    v[d4 * 4 + 2] = vv.z + bv.z; v[d4 * 4 + 3] = vv.w + bv.w;
                }
                float rr[32];
#pragma unroll
                for (int j = 0; j < 16; ++j) {
                    float2 cs = tbl[n * 16 + j];
                    float a0 = v[2 * j], a1 = v[2 * j + 1];
                    rr[2 * j]     = a0 * cs.x - a1 * cs.y;
                    rr[2 * j + 1] = a1 * cs.x + a0 * cs.y;
                }
                float n2 = 0.0f;
#pragma unroll
                for (int d = 0; d < 32; ++d) n2 = fmaf(rr[d], rr[d], n2);
                const float inv = 1.0f / fmaxf(sqrtf(n2), 1e-12f);
                __hip_bfloat16* dst = qbf + ((size_t)(bg * NH_ + hglob) * 64 + n) * 32;
#pragma unroll
                for (int c8 = 0; c8 < 4; ++c8) {
                    union { uint4 u; __hip_bfloat16 h[8]; } pk;
#pragma unroll
                    for (int i = 0; i < 8; ++i) pk.h[i] = __float2bfloat16(rr[c8 * 8 + i] * inv);
                    *(uint4*)(dst + c8 * 8) = pk.u;
                }
            }
        }
    }
}

// ---------------------------------------------------------------------------
// Kernel 3 (MFMA): attention for one (bg, head). K from token-major xsk
// (pre-normalized; rope only), V from channel-major xsv. XCD-chunk swizzle.
// ---------------------------------------------------------------------------
__global__ __launch_bounds__(512, 2)
void k_attn(const __hip_bfloat16* __restrict__ xsk, const __hip_bfloat16* __restrict__ xsv,
            const unsigned int* __restrict__ gbits, const __hip_bfloat16* __restrict__ qb,
            const float2* __restrict__ tbl, float* __restrict__ attn)
{
    __shared__ __align__(16) char smem[52736];
    const int bid0 = blockIdx.x;
    const int bid = (bid0 & 7) * 768 + (bid0 >> 3);    // 6144 = 8 x 768, bijective
    const int h = bid % NH_;
    const int bg = bid / NH_;
    const int b = bg >> 8, ph = (bg >> 4) & 15, pw = bg & 15;
    const int t = threadIdx.x;
    const int w = t >> 6, lane = t & 63;
    const int g = lane >> 4, l15 = lane & 15;
    const int rbase = (w & 3) * 16;        // q rows
    const int wcol  = w >> 2;              // kv half
    const int cb    = wcol * 128;
    const int cb32  = wcol * 4;

    // ---- A-frag: Q direct from global (issue early) ----
    const short8v qa = *(const short8v*)(qb +
        ((size_t)(bg * NH_ + h) * 64 + rbase + l15) * 32 + g * 8);

    // ---- stage K (rope only, pre-normalized) into kl: thread=(m,half) ----
    {
        const int m = t >> 1, half = t & 1;
        const int k0 = m >> 4, k1 = m & 15;
        const int rr = ph * 8 - 4 + k0, cc = pw * 8 - 4 + k1;
        const bool inb = ((unsigned)rr < 128u) && ((unsigned)cc < 128u);
        float kv[16];
        if (inb) {
            const uint4* pk = (const uint4*)(xsk +
                ((size_t)b * PIX_ + rr * 128 + cc) * C_ + h * 32 + half * 16);
            union { uint4 u; __hip_bfloat16 h8[8]; } r0, r1;
            r0.u = pk[0]; r1.u = pk[1];
#pragma unroll
            for (int d = 0; d < 8; ++d) {
                kv[d]     = __bfloat162float(r0.h8[d]);
                kv[8 + d] = __bfloat162float(r1.h8[d]);
            }
        } else {
#pragma unroll
            for (int d = 0; d < 16; ++d) kv[d] = 0.0f;
        }
        union { uint4 u; __hip_bfloat16 hh[8]; } p0, p1;
#pragma unroll
        for (int p = 0; p < 8; ++p) {
            float2 cs = tbl[m * 16 + half * 8 + p];
            float a0 = kv[2 * p], a1 = kv[2 * p + 1];
            float e0 = a0 * cs.x - a1 * cs.y;
            float e1 = a1 * cs.x + a0 * cs.y;
            if (p < 4) { p0.hh[2 * p] = __float2bfloat16(e0); p0.hh[2 * p + 1] = __float2bfloat16(e1); }
            else { p1.hh[2 * (p - 4)] = __float2bfloat16(e0); p1.hh[2 * (p - 4) + 1] = __float2bfloat16(e1); }
        }
        *(uint4*)(smem + m * 80 + half * 32)      = p0.u;
        *(uint4*)(smem + m * 80 + half * 32 + 16) = p1.u;
    }

    // ---- stage V transposed into vl[d][kv] (528B rows) ----
    {
        const int d = t & 31, k0 = t >> 5;
        const int rr = ph * 8 - 4 + k0;
        const int c0 = pw * 8 - 4;
        char* dst = smem + 34816 + d * 528 + k0 * 32;
        const __hip_bfloat16* src = xsv + (size_t)(b * C_ + h * 32 + d) * PIX_ + rr * 128 + c0;
        const bool rok = (unsigned)rr < 128u;
        if (rok && pw >= 1 && pw <= 14) {
            const uint2* s2 = (const uint2*)src;   // 8B aligned
            uint2 a0 = s2[0], a1 = s2[1], a2 = s2[2], a3 = s2[3];
            ((uint4*)dst)[0] = make_uint4(a0.x, a0.y, a1.x, a1.y);
            ((uint4*)dst)[1] = make_uint4(a2.x, a2.y, a3.x, a3.y);
        } else {
            __hip_bfloat16* dh = (__hip_bfloat16*)dst;
            __hip_bfloat16 z = __float2bfloat16(0.0f);
#pragma unroll
            for (int i = 0; i < 16; ++i) {
                bool ok = rok && ((unsigned)(c0 + i) < 128u);
                dh[i] = ok ? src[i] : z;
            }
        }
    }

    // ---- stage graph bits: gb[q][9] uints ----
    {
        unsigned int* gbl = (unsigned int*)(smem + 20480);
        const int q = t >> 3, wd = t & 7;
        gbl[q * 9 + wd] = gbits[(size_t)bg * 512 + t];
    }
    __syncthreads();   // sync1

    // ---- sim = Q K^T ----
    f32x4 acc[8];
    const f32x4 zz = {0.0f, 0.0f, 0.0f, 0.0f};
#pragma unroll
    for (int tile = 0; tile < 8; ++tile) {
        const short8v kb = *(const short8v*)(smem + (cb + tile * 16 + l15) * 80 + g * 16);
        acc[tile] = __builtin_amdgcn_mfma_f32_16x16x32_bf16(qa, kb, zz, 0, 0, 0);
    }

    // ---- mask + scale + row max ----
    const unsigned int* gbl = (const unsigned int*)(smem + 20480);
    float* redm = (float*)(smem + 51712);
    float* reds = (float*)(smem + 51712 + 512);
    float mx4[4], Mt[4], sm4[4], inv4[4];
#pragma unroll
    for (int j = 0; j < 4; ++j) {
        const int q = rbase + g * 4 + j;
        const unsigned int wv[4] = { gbl[q * 9 + cb32], gbl[q * 9 + cb32 + 1],
                                     gbl[q * 9 + cb32 + 2], gbl[q * 9 + cb32 + 3] };
        float mx = -3.0e38f;
#pragma unroll
        for (int tile = 0; tile < 8; ++tile) {
            unsigned int bit = (wv[tile >> 1] >> ((tile & 1) * 16 + l15)) & 1u;
            float s = acc[tile][j] * SCALE_ + (bit ? 0.0f : NEGM_);
            acc[tile][j] = s;
            mx = fmaxf(mx, s);
        }
        mx = fmaxf(mx, __shfl_xor(mx, 1));
        mx = fmaxf(mx, __shfl_xor(mx, 2));
        mx = fmaxf(mx, __shfl_xor(mx, 4));
        mx = fmaxf(mx, __shfl_xor(mx, 8));
        mx4[j] = mx;
        if (l15 == 0) redm[wcol * 64 + q] = mx;
    }
    __syncthreads();   // sync2
#pragma unroll
    for (int j = 0; j < 4; ++j) {
        const int q = rbase + g * 4 + j;
        Mt[j] = fmaxf(mx4[j], redm[(wcol ^ 1) * 64 + q]);
        float sm = 0.0f;
#pragma unroll
        for (int tile = 0; tile < 8; ++tile) {
            float e = __expf(acc[tile][j] - Mt[j]);
            acc[tile][j] = e;
            sm += e;
        }
        sm += __shfl_xor(sm, 1);
        sm += __shfl_xor(sm, 2);
        sm += __shfl_xor(sm, 4);
        sm += __shfl_xor(sm, 8);
        sm4[j] = sm;
        if (l15 == 0) reds[wcol * 64 + q] = sm;
    }
    __syncthreads();   // sync3
#pragma unroll
    for (int j = 0; j < 4; ++j) {
        const int q = rbase + g * 4 + j;
        inv4[j] = 1.0f / (sm4[j] + reds[(wcol ^ 1) * 64 + q]);
    }

    // ---- write P (bf16) to per-wave pl region ----
    char* plw = smem + w * 4352;
#pragma unroll
    for (int tile = 0; tile < 8; ++tile)
#pragma unroll
        for (int j = 0; j < 4; ++j) {
            *(__hip_bfloat16*)(plw + (g * 4 + j) * 272 + (tile * 16 + l15) * 2) =
                __float2bfloat16(acc[tile][j] * inv4[j]);
        }

    // ---- PV ----
    f32x4 o0 = zz, o1 = zz;
#pragma unroll
    for (int ks = 0; ks < 4; ++ks) {
        const short8v pa  = *(const short8v*)(plw + l15 * 272 + (ks * 32 + g * 8) * 2);
        const short8v vb0 = *(const short8v*)(smem + 34816 + l15 * 528        + (cb + ks * 32 + g * 8) * 2);
        const short8v vb1 = *(const short8v*)(smem + 34816 + (16 + l15) * 528 + (cb + ks * 32 + g * 8) * 2);
        o0 = __builtin_amdgcn_mfma_f32_16x16x32_bf16(pa, vb0, o0, 0, 0, 0);
        o1 = __builtin_amdgcn_mfma_f32_16x16x32_bf16(pa, vb1, o1, 0, 0, 0);
    }
    __syncthreads();   // sync4

    // ---- cross-half reduce + store ----
    float* ob = (float*)smem;   // [64][33] f32
    if (wcol == 1) {
#pragma unroll
        for (int j = 0; j < 4; ++j) {
            const int q = rbase + g * 4 + j;
            ob[q * 33 + l15]      = o0[j];
            ob[q * 33 + 16 + l15] = o1[j];
        }
    }
    __syncthreads();   // sync5
    if (wcol == 0) {
#pragma unroll
        for (int j = 0; j < 4; ++j) {
            const int q = rbase + g * 4 + j;
            float v0 = o0[j] + ob[q * 33 + l15];
            float v1 = o1[j] + ob[q * 33 + 16 + l15];
            attn[((size_t)bg * 64 + q) * 192 + h * 32 + l15]      = v0;
            attn[((size_t)bg * 64 + q) * 192 + h * 32 + 16 + l15] = v1;
        }
    }
}

// ---------------------------------------------------------------------------
// Kernel 4 (MFMA): final projection out = attn @ wp^T + bp, in-place on d_out.
// ---------------------------------------------------------------------------
__global__ __launch_bounds__(256, 4)
void k_oprojm(const float* __restrict__ attn, const __hip_bfloat16* __restrict__ wpb,
              const float* __restrict__ bp, float* __restrict__ out)
{
    __shared__ __align__(16) char smem[25600];   // at [64r][400B] bf16 / ot f32 [64px][68]
    const int bid0 = blockIdx.x;
    const int bid = (bid0 & 7) * 384 + (bid0 >> 3);   // 3072 = 8 x 384, bijective
    const int oct = bid % 3;
    const int rt  = bid / 3;
    const int row0 = rt * 64;
    const int t = threadIdx.x;

    // ---- stage A: attn[row0..+64][192] f32 -> bf16 LDS (coalesced) ----
#pragma unroll
    for (int e0 = 0; e0 < 12; ++e0) {
        const int e = e0 * 256 + t;          // 3072 float4s
        const int r = e / 48, c4 = e % 48;
        float4 v = *(const float4*)(attn + (size_t)(row0 + r) * 192 + c4 * 4);
        union { uint2 u; __hip_bfloat16 h[4]; } pk;
        pk.h[0] = __float2bfloat16(v.x); pk.h[1] = __float2bfloat16(v.y);
        pk.h[2] = __float2bfloat16(v.z); pk.h[3] = __float2bfloat16(v.w);
        *(uint2*)(smem + r * 400 + c4 * 8) = pk.u;
    }
    __syncthreads();

    const int w = t >> 6, lane = t & 63;
    const int l15 = lane & 15, g = lane >> 4;
    const int mb = (w & 1) * 32;     // row quadrant
    const int nb = (w >> 1) * 32;    // oc quadrant

    const f32x4 zz = {0.0f, 0.0f, 0.0f, 0.0f};
    f32x4 acc00 = zz, acc01 = zz, acc10 = zz, acc11 = zz;
    const __hip_bfloat16* w0 = wpb + (size_t)(oct * 64 + nb + l15) * C_;
    const __hip_bfloat16* w1 = w0 + 16 * C_;
#pragma unroll
    for (int ks = 0; ks < 6; ++ks) {
        const short8v a0 = *(const short8v*)(smem + (mb + l15) * 400      + ks * 64 + g * 16);
        const short8v a1 = *(const short8v*)(smem + (mb + 16 + l15) * 400 + ks * 64 + g * 16);
        const short8v b0 = *(const short8v*)(w0 + ks * 32 + g * 8);
        const short8v b1 = *(const short8v*)(w1 + ks * 32 + g * 8);
        acc00 = __builtin_amdgcn_mfma_f32_16x16x32_bf16(a0, b0, acc00, 0, 0, 0);
        acc01 = __builtin_amdgcn_mfma_f32_16x16x32_bf16(a0, b1, acc01, 0, 0, 0);
        acc10 = __builtin_amdgcn_mfma_f32_16x16x32_bf16(a1, b0, acc10, 0, 0, 0);
        acc11 = __builtin_amdgcn_mfma_f32_16x16x32_bf16(a1, b1, acc11, 0, 0, 0);
    }
    __syncthreads();   // A-frag reads done -> overlay ot

    // ---- store transposed ot[px][oc] (68-float rows) ----
    float* ot = (float*)smem;
#pragma unroll
    for (int j = 0; j < 4; ++j) {
        ot[(mb + g * 4 + j) * 68      + nb + l15]      = acc00[j];
        ot[(mb + 16 + g * 4 + j) * 68 + nb + l15]      = acc10[j];
        ot[(mb + g * 4 + j) * 68      + nb + 16 + l15] = acc01[j];
        ot[(mb + 16 + g * 4 + j) * 68 + nb + 16 + l15] = acc11[j];
    }
    __syncthreads();

    // ---- epilogue: bias + coalesced f32 write ----
    {
        const int k = t & 15, pxi = t >> 4;
        const float4 bias4 = *(const float4*)(bp + oct * 64 + k * 4);
#pragma unroll
        for (int p = 0; p < 4; ++p) {
            const int px = p * 16 + pxi;
            float4 v = *(const float4*)&ot[px * 68 + k * 4];
            v.x += bias4.x; v.y += bias4.y; v.z += bias4.z; v.w += bias4.w;
            *(float4*)(out + (size_t)(row0 + px) * 192 + oct * 64 + k * 4) = v;
        }
    }
}

// ---------------------------------------------------------------------------
extern "C" void kernel_launch(void* const* d_in, const int* in_sizes, int n_in,
                              void* d_out, int out_size, void* d_ws, size_t ws_size,
                              hipStream_t stream)
{
    (void)in_sizes; (void)n_in; (void)out_size; (void)ws_size;
    const float* x   = (const float*)d_in[0];
    const int* grph  = (const int*)d_in[1];     // jnp bool -> int32 per harness
    const float* wg  = (const float*)d_in[2];
    const float* bgb = (const float*)d_in[3];
    const float* wsm = (const float*)d_in[4];
    const float* bsm = (const float*)d_in[5];
    const float* wp  = (const float*)d_in[6];
    const float* bp  = (const float*)d_in[7];
    float* out = (float*)d_out;

    char* wsb = (char*)d_ws;
    __hip_bfloat16* xsk = (__hip_bfloat16*)wsb;                  // 25,165,824 B (K token-major, normalized)
    __hip_bfloat16* xsv = (__hip_bfloat16*)(wsb + 25165824ull);  // 25,165,824 B (V channel-major)
    __hip_bfloat16* qbf = (__hip_bfloat16*)(wsb + 50331648ull);  // 25,165,824 B (q bf16)
    float2* tbl = (float2*)(wsb + 75497472ull);                  // 32,768 B (rope table)
    unsigned int* gbits = (unsigned int*)(wsb + 75530240ull);    // 2,097,152 B (graph bits)
    __hip_bfloat16* wb  = (__hip_bfloat16*)(wsb + 77627392ull);  // 221,184 B (ws+wg bf16)
    __hip_bfloat16* wpb = wb + 110592;                           // 73,728 B (wp bf16)

    hipLaunchKernelGGL(k_rope_init, dim3(16),   dim3(256), 0, stream, tbl);
    hipLaunchKernelGGL(k_wcast,     dim3(144),  dim3(256), 0, stream, wsm, wg, wp, wb);
    hipLaunchKernelGGL(k_gmask,     dim3(2048), dim3(256), 0, stream, grph, gbits);
    hipLaunchKernelGGL(k_convm,     dim3(1024), dim3(256), 0, stream, x, wb, bsm, bgb, tbl, xsk, xsv, qbf);
    hipLaunchKernelGGL(k_attn,      dim3(6144), dim3(512), 0, stream, xsk, xsv, gbits, qbf, tbl, out);
    hipLaunchKernelGGL(k_oprojm,    dim3(3072), dim3(256), 0, stream, out, wpb, bp, out);
}

// Round 8
// 196.679 us; speedup vs baseline: 4.0940x; 1.0570x over previous
//
#include <hip/hip_runtime.h>
#include <hip/hip_bf16.h>

// Problem constants
#define B_    4
#define C_    192
#define C2_   384
#define PIX_  16384      // 128*128
#define NH_   6
#define BG_   1024
#define SCALE_ 0.17677669529663687f   // 32^-0.5
// exp(s*SCALE - SCALE) == exp2(fmaf(s, C1, -C1)), C1 = SCALE*log2(e).
// Valid because |s|<=1 (cosine of unit vectors) -> constant max M=1 is safe.
#define C1_ 0.2550348943f

typedef __attribute__((ext_vector_type(8))) short short8v;   // 8 bf16 = 4 VGPR
typedef __attribute__((ext_vector_type(4))) float f32x4;

// ---------------------------------------------------------------------------
// Kernel 0: RoPE cos/sin table
// ---------------------------------------------------------------------------
__global__ __launch_bounds__(256, 1)
void k_rope_init(float2* __restrict__ tbl) {
    int e = blockIdx.x * 256 + threadIdx.x;    // 4096 entries
    if (e >= 4096) return;
    int pos = e >> 4, j = e & 15;
    float freq = powf(10.0f, -0.25f * (float)j);
    float ang = (float)pos * freq;
    float sn, cs;
    sincosf(ang, &sn, &cs);
    tbl[e] = make_float2(cs, sn);
}

// ---------------------------------------------------------------------------
// Kernel 0b: graph int32 -> bitmask
// ---------------------------------------------------------------------------
__global__ __launch_bounds__(256, 4)
void k_gmask(const int* __restrict__ g, unsigned int* __restrict__ gbits) {
    int e = blockIdx.x * 256 + threadIdx.x;            // 524288 dwords
    const uint4* p = (const uint4*)(g + (size_t)e * 32);
    unsigned int m = 0u;
#pragma unroll
    for (int i = 0; i < 8; ++i) {
        uint4 v = p[i];
        m |= (v.x ? 1u : 0u) << (i * 4);
        m |= (v.y ? 1u : 0u) << (i * 4 + 1);
        m |= (v.z ? 1u : 0u) << (i * 4 + 2);
        m |= (v.w ? 1u : 0u) << (i * 4 + 3);
    }
    gbits[e] = m;
}

// ---------------------------------------------------------------------------
// Kernel 0c: cast w_sample ++ w_group ++ w_proj -> bf16
// ---------------------------------------------------------------------------
__global__ __launch_bounds__(256, 4)
void k_wcast(const float* __restrict__ wsm, const float* __restrict__ wgb,
             const float* __restrict__ wpj, __hip_bfloat16* __restrict__ wb)
{
    int e = (blockIdx.x * 256 + threadIdx.x) * 4;      // 147456 elems
    float4 v = (e < 73728) ? *(const float4*)(wsm + e)
             : (e < 110592) ? *(const float4*)(wgb + (e - 73728))
                            : *(const float4*)(wpj + (e - 110592));
    union { uint2 u; __hip_bfloat16 h[4]; } pk;
    pk.h[0] = __float2bfloat16(v.x); pk.h[1] = __float2bfloat16(v.y);
    pk.h[2] = __float2bfloat16(v.z); pk.h[3] = __float2bfloat16(v.w);
    *(uint2*)(wb + e) = pk.u;
}

// ---------------------------------------------------------------------------
// Kernel 1 (MFMA): fused 1x1 conv 192 -> 576, ONE block per 64-px tile.
// ---------------------------------------------------------------------------
__global__ __launch_bounds__(256, 4)
void k_convm(const float* __restrict__ x, const __hip_bfloat16* __restrict__ wb,
             const float* __restrict__ bsm, const float* __restrict__ bgb,
             const float2* __restrict__ tbl,
             __hip_bfloat16* __restrict__ xsk, __hip_bfloat16* __restrict__ xsv,
             __hip_bfloat16* __restrict__ qbf)
{
    __shared__ __align__(16) char smem[25600];   // xt [64px][400B] -> ot f32 [64][68]
    const int bid = blockIdx.x;                  // 1024 = b(4) x pt(256)
    const int b = bid >> 8, pt = bid & 255;
    const int px0 = pt * 64;
    const int t = threadIdx.x;

    // ---- stage x tile [64 px][192 c] -> bf16 LDS, transposed (once) ----
    {
        const int px = t & 63, cq = t >> 6;
        const float* src = x + ((size_t)b * C_ + cq * 48) * PIX_ + px0 + px;
        char* row = smem + px * 400 + cq * 96;
#pragma unroll
        for (int i = 0; i < 6; ++i) {
            union { uint4 u; __hip_bfloat16 h[8]; } pk;
#pragma unroll
            for (int j = 0; j < 8; ++j)
                pk.h[j] = __float2bfloat16(src[(size_t)(i * 8 + j) * PIX_]);
            *(uint4*)(row + i * 16) = pk.u;
        }
    }
    __syncthreads();

    const int w = t >> 6, lane = t & 63;
    const int l15 = lane & 15, g = lane >> 4;
    const int mb = (w & 1) * 32;     // px quadrant
    const int nb = (w >> 1) * 32;    // oc quadrant

    // ---- hoist A-frags to registers (same for all 9 octs) ----
    short8v a0r[6], a1r[6];
#pragma unroll
    for (int ks = 0; ks < 6; ++ks) {
        a0r[ks] = *(const short8v*)(smem + (mb + l15) * 400      + ks * 64 + g * 16);
        a1r[ks] = *(const short8v*)(smem + (mb + 16 + l15) * 400 + ks * 64 + g * 16);
    }
    __syncthreads();   // xt dead -> ot overlays

    float* ot = (float*)smem;
    const f32x4 zz = {0.0f, 0.0f, 0.0f, 0.0f};

    for (int oct = 0; oct < 9; ++oct) {
        f32x4 acc00 = zz, acc01 = zz, acc10 = zz, acc11 = zz;
        const __hip_bfloat16* w0 = wb + (size_t)(oct * 64 + nb + l15) * C_;
        const __hip_bfloat16* w1 = w0 + 16 * C_;
#pragma unroll
        for (int ks = 0; ks < 6; ++ks) {
            const short8v b0 = *(const short8v*)(w0 + ks * 32 + g * 8);
            const short8v b1 = *(const short8v*)(w1 + ks * 32 + g * 8);
            acc00 = __builtin_amdgcn_mfma_f32_16x16x32_bf16(a0r[ks], b0, acc00, 0, 0, 0);
            acc01 = __builtin_amdgcn_mfma_f32_16x16x32_bf16(a0r[ks], b1, acc01, 0, 0, 0);
            acc10 = __builtin_amdgcn_mfma_f32_16x16x32_bf16(a1r[ks], b0, acc10, 0, 0, 0);
            acc11 = __builtin_amdgcn_mfma_f32_16x16x32_bf16(a1r[ks], b1, acc11, 0, 0, 0);
        }
        __syncthreads();   // previous epilogue's ot reads done

        if (oct >= 3 && oct < 6) {
            // V branch: ot[oc][px]
            *(f32x4*)&ot[(nb + l15) * 68      + mb + g * 4]      = acc00;
            *(f32x4*)&ot[(nb + l15) * 68      + mb + 16 + g * 4] = acc10;
            *(f32x4*)&ot[(nb + 16 + l15) * 68 + mb + g * 4]      = acc01;
            *(f32x4*)&ot[(nb + 16 + l15) * 68 + mb + 16 + g * 4] = acc11;
        } else {
            // K / q branches: transposed ot[px][oc]
#pragma unroll
            for (int j = 0; j < 4; ++j) {
                ot[(mb + g * 4 + j) * 68      + nb + l15]      = acc00[j];
                ot[(mb + 16 + g * 4 + j) * 68 + nb + l15]      = acc10[j];
                ot[(mb + g * 4 + j) * 68      + nb + 16 + l15] = acc01[j];
                ot[(mb + 16 + g * 4 + j) * 68 + nb + 16 + l15] = acc11[j];
            }
        }
        __syncthreads();

        if (oct < 3) {
            // K: bias + l2norm (per head = 2 threads), token-major write
            const int px = t >> 2, i = t & 3;
            const int ocb = oct * 64 + i * 16;
            float v[16];
#pragma unroll
            for (int q4 = 0; q4 < 4; ++q4) {
                float4 vv = *(const float4*)&ot[px * 68 + i * 16 + q4 * 4];
                float4 bv = *(const float4*)(bsm + ocb + q4 * 4);
                v[q4 * 4 + 0] = vv.x + bv.x; v[q4 * 4 + 1] = vv.y + bv.y;
                v[q4 * 4 + 2] = vv.z + bv.z; v[q4 * 4 + 3] = vv.w + bv.w;
            }
            float n2 = 0.0f;
#pragma unroll
            for (int d = 0; d < 16; ++d) n2 = fmaf(v[d], v[d], n2);
            n2 += __shfl_xor(n2, 1);             // partner half of same head
            const float inv = 1.0f / fmaxf(sqrtf(n2), 1e-12f);
            union { uint4 u[2]; __hip_bfloat16 h[16]; } pk;
#pragma unroll
            for (int d = 0; d < 16; ++d) pk.h[d] = __float2bfloat16(v[d] * inv);
            __hip_bfloat16* dst = xsk + ((size_t)b * PIX_ + px0 + px) * C_ + ocb;
            *(uint4*)dst       = pk.u[0];
            *(uint4*)(dst + 8) = pk.u[1];
        } else if (oct < 6) {
            // V: bias, channel-major write
            const float* bias = bsm + oct * 64;
#pragma unroll
            for (int e0 = 0; e0 < 2; ++e0) {
                const int e = e0 * 256 + t;
                const int oc = e >> 3, seg = e & 7;
                const float bo = bias[oc];
                float4 v0 = *(const float4*)&ot[oc * 68 + seg * 8];
                float4 v1 = *(const float4*)&ot[oc * 68 + seg * 8 + 4];
                union { uint4 u; __hip_bfloat16 h[8]; } pk;
                pk.h[0] = __float2bfloat16(v0.x + bo); pk.h[1] = __float2bfloat16(v0.y + bo);
                pk.h[2] = __float2bfloat16(v0.z + bo); pk.h[3] = __float2bfloat16(v0.w + bo);
                pk.h[4] = __float2bfloat16(v1.x + bo); pk.h[5] = __float2bfloat16(v1.y + bo);
                pk.h[6] = __float2bfloat16(v1.z + bo); pk.h[7] = __float2bfloat16(v1.w + bo);
                *(uint4*)(xsv + (size_t)(b * C_ + (oct - 3) * 64 + oc) * PIX_ + px0 + seg * 8) = pk.u;
            }
        } else {
            // q: bias + RoPE + l2norm; 2 heads in this tile
            const int px = t & 63, hh = t >> 6;
            if (hh < 2) {
                const int p = px0 + px;
                const int r = p >> 7, c = p & 127;
                const int n = (r & 7) * 8 + (c & 7);
                const int bg = (b << 8) + ((r >> 3) << 4) + (c >> 3);
                const int hglob = (oct - 6) * 2 + hh;
                float v[32];
#pragma unroll
                for (int d4 = 0; d4 < 8; ++d4) {
                    float4 vv = *(const float4*)&ot[px * 68 + hh * 32 + d4 * 4];
                    float4 bv = *(const float4*)(bgb + hglob * 32 + d4 * 4);
                    v[d4 * 4 + 0] = vv.x + bv.x; v[d4 * 4 + 1] = vv.y + bv.y;
                    v[d4 * 4 + 2] = vv.z + bv.z; v[d4 * 4 + 3] = vv.w + bv.w;
                }
                float rr[32];
#pragma unroll
                for (int j = 0; j < 16; ++j) {
                    float2 cs = tbl[n * 16 + j];
                    float a0 = v[2 * j], a1 = v[2 * j + 1];
                    rr[2 * j]     = a0 * cs.x - a1 * cs.y;
                    rr[2 * j + 1] = a1 * cs.x + a0 * cs.y;
                }
                float n2 = 0.0f;
#pragma unroll
                for (int d = 0; d < 32; ++d) n2 = fmaf(rr[d], rr[d], n2);
                const float inv = 1.0f / fmaxf(sqrtf(n2), 1e-12f);
                __hip_bfloat16* dst = qbf + ((size_t)(bg * NH_ + hglob) * 64 + n) * 32;
#pragma unroll
                for (int c8 = 0; c8 < 4; ++c8) {
                    union { uint4 u; __hip_bfloat16 h[8]; } pk;
#pragma unroll
                    for (int i = 0; i < 8; ++i) pk.h[i] = __float2bfloat16(rr[c8 * 8 + i] * inv);
                    *(uint4*)(dst + c8 * 8) = pk.u;
                }
            }
        }
    }
}

// ---------------------------------------------------------------------------
// Kernel 3 (MFMA): attention for one (bg, head).
// Softmax: NO max pass -- q,k unit vectors => sim in [-1,1] => constant
// shift M=1 is overflow-safe. Mask applied multiplicatively (additive -100
// == exact 0 at f32 precision). P stored unnormalized; 1/sum applied to O.
// ---------------------------------------------------------------------------
__global__ __launch_bounds__(512, 2)
void k_attn(const __hip_bfloat16* __restrict__ xsk, const __hip_bfloat16* __restrict__ xsv,
            const unsigned int* __restrict__ gbits, const __hip_bfloat16* __restrict__ qb,
            const float2* __restrict__ tbl, float* __restrict__ attn)
{
    __shared__ __align__(16) char smem[52736];
    const int bid0 = blockIdx.x;
    const int bid = (bid0 & 7) * 768 + (bid0 >> 3);    // 6144 = 8 x 768, bijective
    const int h = bid % NH_;
    const int bg = bid / NH_;
    const int b = bg >> 8, ph = (bg >> 4) & 15, pw = bg & 15;
    const int t = threadIdx.x;
    const int w = t >> 6, lane = t & 63;
    const int g = lane >> 4, l15 = lane & 15;
    const int rbase = (w & 3) * 16;        // q rows
    const int wcol  = w >> 2;              // kv half
    const int cb    = wcol * 128;
    const int cb32  = wcol * 4;

    // ---- A-frag: Q direct from global (issue early) ----
    const short8v qa = *(const short8v*)(qb +
        ((size_t)(bg * NH_ + h) * 64 + rbase + l15) * 32 + g * 8);

    // ---- stage K (rope only, pre-normalized) into kl: thread=(m,half) ----
    {
        const int m = t >> 1, half = t & 1;
        const int k0 = m >> 4, k1 = m & 15;
        const int rr = ph * 8 - 4 + k0, cc = pw * 8 - 4 + k1;
        const bool inb = ((unsigned)rr < 128u) && ((unsigned)cc < 128u);
        float kv[16];
        if (inb) {
            const uint4* pk = (const uint4*)(xsk +
                ((size_t)b * PIX_ + rr * 128 + cc) * C_ + h * 32 + half * 16);
            union { uint4 u; __hip_bfloat16 h8[8]; } r0, r1;
            r0.u = pk[0]; r1.u = pk[1];
#pragma unroll
            for (int d = 0; d < 8; ++d) {
                kv[d]     = __bfloat162float(r0.h8[d]);
                kv[8 + d] = __bfloat162float(r1.h8[d]);
            }
        } else {
#pragma unroll
            for (int d = 0; d < 16; ++d) kv[d] = 0.0f;
        }
        union { uint4 u; __hip_bfloat16 hh[8]; } p0, p1;
#pragma unroll
        for (int p = 0; p < 8; ++p) {
            float2 cs = tbl[m * 16 + half * 8 + p];
            float a0 = kv[2 * p], a1 = kv[2 * p + 1];
            float e0 = a0 * cs.x - a1 * cs.y;
            float e1 = a1 * cs.x + a0 * cs.y;
            if (p < 4) { p0.hh[2 * p] = __float2bfloat16(e0); p0.hh[2 * p + 1] = __float2bfloat16(e1); }
            else { p1.hh[2 * (p - 4)] = __float2bfloat16(e0); p1.hh[2 * (p - 4) + 1] = __float2bfloat16(e1); }
        }
        *(uint4*)(smem + m * 80 + half * 32)      = p0.u;
        *(uint4*)(smem + m * 80 + half * 32 + 16) = p1.u;
    }

    // ---- stage V transposed into vl[d][kv] (528B rows) ----
    {
        const int d = t & 31, k0 = t >> 5;
        const int rr = ph * 8 - 4 + k0;
        const int c0 = pw * 8 - 4;
        char* dst = smem + 34816 + d * 528 + k0 * 32;
        const __hip_bfloat16* src = xsv + (size_t)(b * C_ + h * 32 + d) * PIX_ + rr * 128 + c0;
        const bool rok = (unsigned)rr < 128u;
        if (rok && pw >= 1 && pw <= 14) {
            const uint2* s2 = (const uint2*)src;   // 8B aligned
            uint2 a0 = s2[0], a1 = s2[1], a2 = s2[2], a3 = s2[3];
            ((uint4*)dst)[0] = make_uint4(a0.x, a0.y, a1.x, a1.y);
            ((uint4*)dst)[1] = make_uint4(a2.x, a2.y, a3.x, a3.y);
        } else {
            __hip_bfloat16* dh = (__hip_bfloat16*)dst;
            __hip_bfloat16 z = __float2bfloat16(0.0f);
#pragma unroll
            for (int i = 0; i < 16; ++i) {
                bool ok = rok && ((unsigned)(c0 + i) < 128u);
                dh[i] = ok ? src[i] : z;
            }
        }
    }

    // ---- stage graph bits: gb[q][9] uints ----
    {
        unsigned int* gbl = (unsigned int*)(smem + 20480);
        const int q = t >> 3, wd = t & 7;
        gbl[q * 9 + wd] = gbits[(size_t)bg * 512 + t];
    }
    __syncthreads();   // sync1

    // ---- sim = Q K^T ----
    f32x4 acc[8];
    const f32x4 zz = {0.0f, 0.0f, 0.0f, 0.0f};
#pragma unroll
    for (int tile = 0; tile < 8; ++tile) {
        const short8v kb = *(const short8v*)(smem + (cb + tile * 16 + l15) * 80 + g * 16);
        acc[tile] = __builtin_amdgcn_mfma_f32_16x16x32_bf16(qa, kb, zz, 0, 0, 0);
    }

    // ---- masked exp (constant max) + row sum ----
    const unsigned int* gbl = (const unsigned int*)(smem + 20480);
    float* reds = (float*)(smem + 51712);
    float sm4[4], inv4[4];
#pragma unroll
    for (int j = 0; j < 4; ++j) {
        const int q = rbase + g * 4 + j;
        const unsigned int wv[4] = { gbl[q * 9 + cb32], gbl[q * 9 + cb32 + 1],
                                     gbl[q * 9 + cb32 + 2], gbl[q * 9 + cb32 + 3] };
        float sm = 0.0f;
#pragma unroll
        for (int tile = 0; tile < 8; ++tile) {
            const unsigned int bit = (wv[tile >> 1] >> ((tile & 1) * 16 + l15)) & 1u;
            float e = __builtin_amdgcn_exp2f(fmaf(acc[tile][j], C1_, -C1_));
            e = bit ? e : 0.0f;
            acc[tile][j] = e;
            sm += e;
        }
        sm += __shfl_xor(sm, 1);
        sm += __shfl_xor(sm, 2);
        sm += __shfl_xor(sm, 4);
        sm += __shfl_xor(sm, 8);
        sm4[j] = sm;
        if (l15 == 0) reds[wcol * 64 + q] = sm;
    }
    __syncthreads();   // sync2 (sum exchange)
#pragma unroll
    for (int j = 0; j < 4; ++j) {
        const int q = rbase + g * 4 + j;
        inv4[j] = 1.0f / (sm4[j] + reds[(wcol ^ 1) * 64 + q] + 1e-37f);
    }

    // ---- write P (bf16, UNNORMALIZED) to per-wave pl region ----
    char* plw = smem + w * 4352;
#pragma unroll
    for (int tile = 0; tile < 8; ++tile)
#pragma unroll
        for (int j = 0; j < 4; ++j) {
            *(__hip_bfloat16*)(plw + (g * 4 + j) * 272 + (tile * 16 + l15) * 2) =
                __float2bfloat16(acc[tile][j]);
        }

    // ---- PV ----
    f32x4 o0 = zz, o1 = zz;
#pragma unroll
    for (int ks = 0; ks < 4; ++ks) {
        const short8v pa  = *(const short8v*)(plw + l15 * 272 + (ks * 32 + g * 8) * 2);
        const short8v vb0 = *(const short8v*)(smem + 34816 + l15 * 528        + (cb + ks * 32 + g * 8) * 2);
        const short8v vb1 = *(const short8v*)(smem + 34816 + (16 + l15) * 528 + (cb + ks * 32 + g * 8) * 2);
        o0 = __builtin_amdgcn_mfma_f32_16x16x32_bf16(pa, vb0, o0, 0, 0, 0);
        o1 = __builtin_amdgcn_mfma_f32_16x16x32_bf16(pa, vb1, o1, 0, 0, 0);
    }
    __syncthreads();   // sync3

    // ---- cross-half reduce + normalize-on-output + store ----
    float* ob = (float*)smem;   // [64][33] f32
    if (wcol == 1) {
#pragma unroll
        for (int j = 0; j < 4; ++j) {
            const int q = rbase + g * 4 + j;
            ob[q * 33 + l15]      = o0[j];
            ob[q * 33 + 16 + l15] = o1[j];
        }
    }
    __syncthreads();   // sync4
    if (wcol == 0) {
#pragma unroll
        for (int j = 0; j < 4; ++j) {
            const int q = rbase + g * 4 + j;
            float v0 = (o0[j] + ob[q * 33 + l15])      * inv4[j];
            float v1 = (o1[j] + ob[q * 33 + 16 + l15]) * inv4[j];
            attn[((size_t)bg * 64 + q) * 192 + h * 32 + l15]      = v0;
            attn[((size_t)bg * 64 + q) * 192 + h * 32 + 16 + l15] = v1;
        }
    }
}

// ---------------------------------------------------------------------------
// Kernel 4 (MFMA): final projection out = attn @ wp^T + bp, in-place on d_out.
// ---------------------------------------------------------------------------
__global__ __launch_bounds__(256, 4)
void k_oprojm(const float* __restrict__ attn, const __hip_bfloat16* __restrict__ wpb,
              const float* __restrict__ bp, float* __restrict__ out)
{
    __shared__ __align__(16) char smem[25600];   // at [64r][400B] bf16 / ot f32 [64px][68]
    const int bid0 = blockIdx.x;
    const int bid = (bid0 & 7) * 384 + (bid0 >> 3);   // 3072 = 8 x 384, bijective
    const int oct = bid % 3;
    const int rt  = bid / 3;
    const int row0 = rt * 64;
    const int t = threadIdx.x;

    // ---- stage A: attn[row0..+64][192] f32 -> bf16 LDS (coalesced) ----
#pragma unroll
    for (int e0 = 0; e0 < 12; ++e0) {
        const int e = e0 * 256 + t;          // 3072 float4s
        const int r = e / 48, c4 = e % 48;
        float4 v = *(const float4*)(attn + (size_t)(row0 + r) * 192 + c4 * 4);
        union { uint2 u; __hip_bfloat16 h[4]; } pk;
        pk.h[0] = __float2bfloat16(v.x); pk.h[1] = __float2bfloat16(v.y);
        pk.h[2] = __float2bfloat16(v.z); pk.h[3] = __float2bfloat16(v.w);
        *(uint2*)(smem + r * 400 + c4 * 8) = pk.u;
    }
    __syncthreads();

    const int w = t >> 6, lane = t & 63;
    const int l15 = lane & 15, g = lane >> 4;
    const int mb = (w & 1) * 32;     // row quadrant
    const int nb = (w >> 1) * 32;    // oc quadrant

    const f32x4 zz = {0.0f, 0.0f, 0.0f, 0.0f};
    f32x4 acc00 = zz, acc01 = zz, acc10 = zz, acc11 = zz;
    const __hip_bfloat16* w0 = wpb + (size_t)(oct * 64 + nb + l15) * C_;
    const __hip_bfloat16* w1 = w0 + 16 * C_;
#pragma unroll
    for (int ks = 0; ks < 6; ++ks) {
        const short8v a0 = *(const short8v*)(smem + (mb + l15) * 400      + ks * 64 + g * 16);
        const short8v a1 = *(const short8v*)(smem + (mb + 16 + l15) * 400 + ks * 64 + g * 16);
        const short8v b0 = *(const short8v*)(w0 + ks * 32 + g * 8);
        const short8v b1 = *(const short8v*)(w1 + ks * 32 + g * 8);
        acc00 = __builtin_amdgcn_mfma_f32_16x16x32_bf16(a0, b0, acc00, 0, 0, 0);
        acc01 = __builtin_amdgcn_mfma_f32_16x16x32_bf16(a0, b1, acc01, 0, 0, 0);
        acc10 = __builtin_amdgcn_mfma_f32_16x16x32_bf16(a1, b0, acc10, 0, 0, 0);
        acc11 = __builtin_amdgcn_mfma_f32_16x16x32_bf16(a1, b1, acc11, 0, 0, 0);
    }
    __syncthreads();   // A-frag reads done -> overlay ot

    // ---- store transposed ot[px][oc] (68-float rows) ----
    float* ot = (float*)smem;
#pragma unroll
    for (int j = 0; j < 4; ++j) {
        ot[(mb + g * 4 + j) * 68      + nb + l15]      = acc00[j];
        ot[(mb + 16 + g * 4 + j) * 68 + nb + l15]      = acc10[j];
        ot[(mb + g * 4 + j) * 68      + nb + 16 + l15] = acc01[j];
        ot[(mb + 16 + g * 4 + j) * 68 + nb + 16 + l15] = acc11[j];
    }
    __syncthreads();

    // ---- epilogue: bias + coalesced f32 write ----
    {
        const int k = t & 15, pxi = t >> 4;
        const float4 bias4 = *(const float4*)(bp + oct * 64 + k * 4);
#pragma unroll
        for (int p = 0; p < 4; ++p) {
            const int px = p * 16 + pxi;
            float4 v = *(const float4*)&ot[px * 68 + k * 4];
            v.x += bias4.x; v.y += bias4.y; v.z += bias4.z; v.w += bias4.w;
            *(float4*)(out + (size_t)(row0 + px) * 192 + oct * 64 + k * 4) = v;
        }
    }
}

// ---------------------------------------------------------------------------
extern "C" void kernel_launch(void* const* d_in, const int* in_sizes, int n_in,
                              void* d_out, int out_size, void* d_ws, size_t ws_size,
                              hipStream_t stream)
{
    (void)in_sizes; (void)n_in; (void)out_size; (void)ws_size;
    const float* x   = (const float*)d_in[0];
    const int* grph  = (const int*)d_in[1];     // jnp bool -> int32 per harness
    const float* wg  = (const float*)d_in[2];
    const float* bgb = (const float*)d_in[3];
    const float* wsm = (const float*)d_in[4];
    const float* bsm = (const float*)d_in[5];
    const float* wp  = (const float*)d_in[6];
    const float* bp  = (const float*)d_in[7];
    float* out = (float*)d_out;

    char* wsb = (char*)d_ws;
    __hip_bfloat16* xsk = (__hip_bfloat16*)wsb;                  // 25,165,824 B (K token-major, normalized)
    __hip_bfloat16* xsv = (__hip_bfloat16*)(wsb + 25165824ull);  // 25,165,824 B (V channel-major)
    __hip_bfloat16* qbf = (__hip_bfloat16*)(wsb + 50331648ull);  // 25,165,824 B (q bf16)
    float2* tbl = (float2*)(wsb + 75497472ull);                  // 32,768 B (rope table)
    unsigned int* gbits = (unsigned int*)(wsb + 75530240ull);    // 2,097,152 B (graph bits)
    __hip_bfloat16* wb  = (__hip_bfloat16*)(wsb + 77627392ull);  // 221,184 B (ws+wg bf16)
    __hip_bfloat16* wpb = wb + 110592;                           // 73,728 B (wp bf16)

    hipLaunchKernelGGL(k_rope_init, dim3(16),   dim3(256), 0, stream, tbl);
    hipLaunchKernelGGL(k_wcast,     dim3(144),  dim3(256), 0, stream, wsm, wg, wp, wb);
    hipLaunchKernelGGL(k_gmask,     dim3(2048), dim3(256), 0, stream, grph, gbits);
    hipLaunchKernelGGL(k_convm,     dim3(1024), dim3(256), 0, stream, x, wb, bsm, bgb, tbl, xsk, xsv, qbf);
    hipLaunchKernelGGL(k_attn,      dim3(6144), dim3(512), 0, stream, xsk, xsv, gbits, qbf, tbl, out);
    hipLaunchKernelGGL(k_oprojm,    dim3(3072), dim3(256), 0, stream, out, wpb, bp, out);
}